// Round 9
// baseline (355.916 us; speedup 1.0000x reference)
//
#include <hip/hip_runtime.h>
#include <math.h>

#define NB 4
#define TT 1024
#define DD 1024
#define NTOK 4096
#define ND (NTOK*DD)

typedef __attribute__((ext_vector_type(8))) short bh8;
typedef __attribute__((ext_vector_type(4))) float fx4;

__device__ __forceinline__ unsigned short f2bf(float f) {
    unsigned int b = __float_as_uint(f);
    b += 0x7fffu + ((b >> 16) & 1u);
    return (unsigned short)(b >> 16);
}

// pack two fp32 -> packed bf16 (RNE); HW v_cvt_pk_bf16_f32 when available
__device__ __forceinline__ unsigned pkbf(float a, float b) {
#if __has_builtin(__builtin_amdgcn_cvt_pk_bf16_f32)
    auto r = __builtin_amdgcn_cvt_pk_bf16_f32(a, b);
    unsigned u;
    __builtin_memcpy(&u, &r, 4);
    return u;
#else
    return ((unsigned)f2bf(b) << 16) | f2bf(a);
#endif
}

// async global->LDS, 16B per lane, LDS dst = wave-uniform base + lane*16
#define GLD16(gp, lp) __builtin_amdgcn_global_load_lds( \
    (__attribute__((address_space(1))) void*)(gp), \
    (__attribute__((address_space(3))) void*)(lp), 16, 0, 0)

// barrier that is also a compiler memory fence
#define BARF() do { __builtin_amdgcn_s_barrier(); asm volatile("" ::: "memory"); } while (0)

// ---------- fused preprocessing: 5x wconv, w1T, dw1T, w2T ----------
__global__ __launch_bounds__(256) void k_prep(const float* __restrict__ W_r, const float* __restrict__ W_k,
                                              const float* __restrict__ W_v, const float* __restrict__ W_g,
                                              const float* __restrict__ W_o,
                                              const float* __restrict__ w1, const float* __restrict__ dw1,
                                              const float* __restrict__ w2,
                                              unsigned short* __restrict__ Wrb, unsigned short* __restrict__ Wkb,
                                              unsigned short* __restrict__ Wvb, unsigned short* __restrict__ Wgb,
                                              unsigned short* __restrict__ Wob,
                                              unsigned short* __restrict__ w1T, unsigned short* __restrict__ dw1T,
                                              unsigned short* __restrict__ w2T16) {
    int y = blockIdx.y, bx = blockIdx.x, tid = threadIdx.x;   // grid (640, 7)
    if (y < 5) {
        if (bx >= 512) return;
        const float* s = (y == 0) ? W_r : (y == 1) ? W_k : (y == 2) ? W_v : (y == 3) ? W_g : W_o;
        unsigned short* d = (y == 0) ? Wrb : (y == 1) ? Wkb : (y == 2) ? Wvb : (y == 3) ? Wgb : Wob;
        int i = (bx * 256 + tid) * 8;
        float4 a = *(const float4*)(s + i);
        float4 b = *(const float4*)(s + i + 4);
        uint4 o;
        o.x = pkbf(a.x, a.y);
        o.y = pkbf(a.z, a.w);
        o.z = pkbf(b.x, b.y);
        o.w = pkbf(b.z, b.w);
        *(uint4*)(d + i) = o;
    } else if (y == 5) {
        int o = bx * 256 + tid;          // 163840 total
        int r = o & 1023, c = o >> 10;
        w1T[o] = f2bf(w1[r * 160 + c]);
    } else {
        if (bx < 256) {
            int o = bx * 256 + tid;      // 65536 total
            int r = o & 1023, c = o >> 10;
            dw1T[o] = f2bf(dw1[r * 64 + c]);
        } else if (bx < 276) {
            int wi = bx - 256;
            int f = wi >> 2;
            int d = (wi & 3) * 256 + tid;
#pragma unroll 8
            for (int m = 0; m < 32; m++)
                w2T16[(size_t)(f * 1024 + d) * 32 + m] = f2bf(w2[(size_t)(f * 32 + m) * 1024 + d]);
        }
    }
}

// ---------- k1: xmix16 = bf16(x + dxprev * maa_x) ----------
__global__ __launch_bounds__(256) void k_mixx(const float* __restrict__ x,
                                              const float* __restrict__ maa_x,
                                              unsigned short* __restrict__ xmix16) {
    int base = (blockIdx.x * 256 + threadIdx.x) * 4;   // grid 4096
    int t = (base >> 10) & 1023;
    int d = base & 1023;
    float4 xv = *(const float4*)(x + base);
    float4 xm = (t > 0)    ? *(const float4*)(x + base - 1024) : make_float4(0, 0, 0, 0);
    float4 xp = (t < 1023) ? *(const float4*)(x + base + 1024) : make_float4(0, 0, 0, 0);
    float4 ma = *(const float4*)(maa_x + d);
    uint2 o;
    float a0 = xv.x + (0.5f * (xm.x + xp.x) - xv.x) * ma.x;
    float a1 = xv.y + (0.5f * (xm.y + xp.y) - xv.y) * ma.y;
    float a2 = xv.z + (0.5f * (xm.z + xp.z) - xv.z) * ma.z;
    float a3 = xv.w + (0.5f * (xm.w + xp.w) - xv.w) * ma.w;
    o.x = pkbf(a0, a1);
    o.y = pkbf(a2, a3);
    *(uint2*)(xmix16 + base) = o;
}

// ---------- k2: xxx16 = bf16(tanh(xmix @ w1)), 4-wave K-split ----------
__global__ __launch_bounds__(256) void k_xxx2(const unsigned short* __restrict__ xmix16,
                                              const unsigned short* __restrict__ w1T,
                                              unsigned short* __restrict__ xxx16) {
    __shared__ __align__(16) float red[4][10][64][4];   // 40 KB
    int tid = threadIdx.x;
    int lane = tid & 63, wv = tid >> 6;
    int l15 = lane & 15, qd = lane >> 4;
    int m0 = blockIdx.x * 16;    // grid 256
    fx4 acc[10];
#pragma unroll
    for (int nt = 0; nt < 10; nt++)
#pragma unroll
        for (int r = 0; r < 4; r++) acc[nt][r] = 0.f;
    int kb0 = wv * 256;
#pragma unroll 2
    for (int kb = kb0; kb < kb0 + 256; kb += 32) {
        bh8 af = *(const bh8*)(xmix16 + (size_t)(m0 + l15) * 1024 + kb + qd * 8);
#pragma unroll
        for (int nt = 0; nt < 10; nt++) {
            bh8 bf = *(const bh8*)(w1T + (size_t)(nt * 16 + l15) * 1024 + kb + qd * 8);
            acc[nt] = __builtin_amdgcn_mfma_f32_16x16x32_bf16(af, bf, acc[nt], 0, 0, 0);
        }
    }
#pragma unroll
    for (int nt = 0; nt < 10; nt++)
        *(fx4*)&red[wv][nt][lane][0] = acc[nt];
    __syncthreads();
    if (wv == 0) {
#pragma unroll
        for (int nt = 0; nt < 10; nt++) {
            fx4 s = *(const fx4*)&red[0][nt][lane][0];
            s = s + *(const fx4*)&red[1][nt][lane][0];
            s = s + *(const fx4*)&red[2][nt][lane][0];
            s = s + *(const fx4*)&red[3][nt][lane][0];
#pragma unroll
            for (int r = 0; r < 4; r++)
                xxx16[(size_t)(m0 + qd * 4 + r) * 160 + nt * 16 + l15] = f2bf(tanhf(s[r]));
        }
    }
}

// ---------- k3: fused mm-einsum (MFMA, K=32) + five mixes, no LDS ----------
__global__ __launch_bounds__(256, 2) void k_mmix(const float* __restrict__ x,
                                                 const unsigned short* __restrict__ xxx16,
                                                 const unsigned short* __restrict__ w2T16,
                                                 const float* __restrict__ maa_w,
                                                 const float* __restrict__ maa_k,
                                                 const float* __restrict__ maa_v,
                                                 const float* __restrict__ maa_r,
                                                 const float* __restrict__ maa_g,
                                                 unsigned short* __restrict__ xw16,
                                                 unsigned short* __restrict__ xk16,
                                                 unsigned short* __restrict__ xv16,
                                                 unsigned short* __restrict__ xr16,
                                                 unsigned short* __restrict__ xg16) {
    int tid = threadIdx.x;
    int w = tid >> 6, lane = tid & 63, l15 = lane & 15, qd = lane >> 4;
    int n0 = blockIdx.x * 64;               // grid (16, 32)
    int m0w = blockIdx.y * 128 + w * 32;
    const float* maap[5] = {maa_w, maa_k, maa_v, maa_r, maa_g};
    unsigned short* outp[5] = {xw16, xk16, xv16, xr16, xg16};
    float xin[8][4], dxv[8][4];
#pragma unroll
    for (int mi = 0; mi < 2; mi++)
#pragma unroll
        for (int r = 0; r < 4; r++) {
            int tok = m0w + mi * 16 + qd * 4 + r;
            int t = tok & 1023;
#pragma unroll
            for (int ni = 0; ni < 4; ni++) {
                int d = n0 + ni * 16 + l15;
                size_t idx = (size_t)tok * 1024 + d;
                float xv = x[idx];
                float xm1 = (t > 0)    ? x[idx - 1024] : 0.f;
                float xp1 = (t < 1023) ? x[idx + 1024] : 0.f;
                xin[mi * 4 + r][ni] = xv;
                dxv[mi * 4 + r][ni] = 0.5f * (xm1 + xp1) - xv;
            }
        }
#pragma unroll
    for (int f = 0; f < 5; f++) {
        bh8 af[2], bf[4];
#pragma unroll
        for (int mi = 0; mi < 2; mi++)
            af[mi] = *(const bh8*)(xxx16 + (size_t)(m0w + mi * 16 + l15) * 160 + f * 32 + qd * 8);
#pragma unroll
        for (int ni = 0; ni < 4; ni++)
            bf[ni] = *(const bh8*)(w2T16 + (size_t)(f * 1024 + n0 + ni * 16 + l15) * 32 + qd * 8);
        fx4 acc[2][4];
#pragma unroll
        for (int mi = 0; mi < 2; mi++)
#pragma unroll
            for (int ni = 0; ni < 4; ni++) {
#pragma unroll
                for (int r = 0; r < 4; r++) acc[mi][ni][r] = 0.f;
                acc[mi][ni] = __builtin_amdgcn_mfma_f32_16x16x32_bf16(af[mi], bf[ni], acc[mi][ni], 0, 0, 0);
            }
        const float* maa = maap[f];
        unsigned short* op = outp[f];
#pragma unroll
        for (int ni = 0; ni < 4; ni++) {
            float mv = maa[n0 + ni * 16 + l15];
#pragma unroll
            for (int mi = 0; mi < 2; mi++)
#pragma unroll
                for (int r = 0; r < 4; r++) {
                    float o = xin[mi * 4 + r][ni] + dxv[mi * 4 + r][ni] * (mv + acc[mi][ni][r]);
                    op[(size_t)(m0w + mi * 16 + qd * 4 + r) * 1024 + n0 + ni * 16 + l15] = f2bf(o);
                }
        }
    }
}

// ---------- decay GEMM1: dech = tanh(xw @ dw1), 4-wave K-split ----------
__global__ __launch_bounds__(256) void k_dec1m(const unsigned short* __restrict__ xw16,
                                               const unsigned short* __restrict__ dw1T,
                                               float* __restrict__ dech) {
    __shared__ __align__(16) float red[4][4][64][4];    // 16 KB
    int tid = threadIdx.x;
    int lane = tid & 63, wv = tid >> 6;
    int l15 = lane & 15, qd = lane >> 4;
    int m0 = blockIdx.x * 16;    // grid 256
    fx4 acc[4];
#pragma unroll
    for (int nt = 0; nt < 4; nt++)
#pragma unroll
        for (int r = 0; r < 4; r++) acc[nt][r] = 0.f;
    int kb0 = wv * 256;
#pragma unroll 2
    for (int kb = kb0; kb < kb0 + 256; kb += 32) {
        bh8 af = *(const bh8*)(xw16 + (size_t)(m0 + l15) * 1024 + kb + qd * 8);
#pragma unroll
        for (int nt = 0; nt < 4; nt++) {
            bh8 bf = *(const bh8*)(dw1T + (size_t)(nt * 16 + l15) * 1024 + kb + qd * 8);
            acc[nt] = __builtin_amdgcn_mfma_f32_16x16x32_bf16(af, bf, acc[nt], 0, 0, 0);
        }
    }
#pragma unroll
    for (int nt = 0; nt < 4; nt++)
        *(fx4*)&red[wv][nt][lane][0] = acc[nt];
    __syncthreads();
    if (wv == 0) {
#pragma unroll
        for (int nt = 0; nt < 4; nt++) {
            fx4 s = *(const fx4*)&red[0][nt][lane][0];
            s = s + *(const fx4*)&red[1][nt][lane][0];
            s = s + *(const fx4*)&red[2][nt][lane][0];
            s = s + *(const fx4*)&red[3][nt][lane][0];
#pragma unroll
            for (int r = 0; r < 4; r++)
                dech[(size_t)(m0 + qd * 4 + r) * 64 + nt * 16 + l15] = tanhf(s[r]);
        }
    }
}

// ---------- decay GEMM2: ew = -exp(time_decay + dech @ dw2) ----------
__global__ __launch_bounds__(256) void k_dec2(const float* __restrict__ dech,
                                              const float* __restrict__ dw2,
                                              const float* __restrict__ tdec,
                                              float* __restrict__ ew) {
    __shared__ float hl[8][64];
    int tid = threadIdx.x;
    int tok0 = blockIdx.x * 8;     // grid 512
    {
        int l = tid;        hl[l >> 6][l & 63] = dech[tok0 * 64 + l];
        l = tid + 256;      hl[l >> 6][l & 63] = dech[tok0 * 64 + l];
    }
    __syncthreads();
#pragma unroll 1
    for (int c = 0; c < 4; c++) {
        int d = c * 256 + tid;
        float acc[8] = {};
#pragma unroll 8
        for (int j = 0; j < 64; j++) {
            float wv = dw2[j * 1024 + d];
#pragma unroll
            for (int g = 0; g < 8; g++) acc[g] = fmaf(hl[g][j], wv, acc[g]);
        }
        float td = tdec[d];
#pragma unroll
        for (int g = 0; g < 8; g++) ew[(tok0 + g) * 1024 + d] = -expf(td + acc[g]);
    }
}

// ---------- scan stage 1: per-segment sums (seg = 32) ----------
__global__ __launch_bounds__(64) void k_scan1(const float* __restrict__ ew, float* __restrict__ segsum) {
    int bx = blockIdx.x;            // grid 2048 = 4b x 32seg x 16dch
    int b = bx >> 9, seg = (bx >> 4) & 31, dch = bx & 15;
    int d = dch * 64 + threadIdx.x;
    size_t base = ((size_t)(b * 1024 + seg * 32)) * 1024 + d;
    float s = 0.f;
#pragma unroll 8
    for (int t = 0; t < 32; t++) s += ew[base + (size_t)t * 1024];
    segsum[(b * 32 + seg) * 1024 + d] = s;
}

// ---------- scan stage 2+3 fused: local prefix of segsums + emit clipped cf/cb ----------
__global__ __launch_bounds__(64) void k_scan3(const float* __restrict__ ew, const float* __restrict__ segsum,
                                              float* __restrict__ cf, float* __restrict__ cb) {
    int bx = blockIdx.x;            // grid 2048
    int b = bx >> 9, seg = (bx >> 4) & 31, dch = bx & 15;
    int d = dch * 64 + threadIdx.x;
    float run = 0.f, pre = 0.f, off16 = 0.f;
#pragma unroll
    for (int s = 0; s < 32; s++) {
        float tv = segsum[(b * 32 + s) * 1024 + d];
        if (s == seg) pre = run;
        if (s == 16) off16 = run;
        run += tv;
    }
    float e512 = ew[((size_t)(b * 1024 + 512)) * 1024 + d];
    float sb = off16;           // cs[511]
    float sf = off16 + e512;    // cs[512]
    float cum = pre;
    size_t base = ((size_t)(b * 1024 + seg * 32)) * 1024 + d;
#pragma unroll 4
    for (int t = 0; t < 32; t++) {
        float prev = cum;
        cum += ew[base + (size_t)t * 1024];
        cf[base + (size_t)t * 1024] = fminf(fmaxf(cum - sf, -60.f), 60.f);
        cb[base + (size_t)t * 1024] = fminf(fmaxf(prev - sb, -60.f), 60.f);
    }
}

// ---------- GEMM engine v5: occupancy-first. BM=128, BN templated, BK=32 ----------
// Wide  (NW=8, BN=256): 512 thr, wave 64x64 (64 AGPR), regs forced <=128 by
//   __launch_bounds__(512,4); LDS ring-3 x 24KB = 72KB -> 2 blocks x 8 waves
//   = 16 waves/CU (4/SIMD). Per wave/tile: 16 MFMA, 8 b128, 3 GLD16 -> vmcnt(3).
// Narrow (NW=4, BN=128): 256 thr, ring-3 x 16KB = 48KB -> 3 blocks/CU (12 waves).
// Zero-conflict swizzle proven in r4: stage gblk = lb ^ ((lr>>1)&3),
// read col qd ^ ((l15>>1)&3). One barrier/tile, counted vmcnt (never 0 till tail).
// modes: 0 fp32 out, 1 silu fp32, 2 q-exp (O1=qf,O2=qb), 3 k-exp, 4 v-transpose (O1=vvt)
template<int NW, int BNv>
__device__ __forceinline__ void gemm_v5(const unsigned short* __restrict__ A,
                                        const unsigned short* __restrict__ W,
                                        int m0, int n0, int mode,
                                        float* __restrict__ Cf,
                                        unsigned short* __restrict__ O1,
                                        unsigned short* __restrict__ O2,
                                        const float* __restrict__ cfp,
                                        const float* __restrict__ cbp,
                                        char* smem) {
    constexpr int AR = 128 / NW;          // A rows staged per wave
    constexpr int AG = AR / 16;           // GLD16s for A per wave
    constexpr int BR = BNv / NW;          // B rows per wave
    constexpr int BG = BR / 16;
    constexpr int LPW = AG + BG;          // loads per wave per tile
    constexpr int SLOT = (128 + BNv) * 64;   // ring slot bytes
    constexpr int WNC = BNv / 64;

    int tid = threadIdx.x;
    int lane = tid & 63, w = tid >> 6;
    int l15 = lane & 15, qd = lane >> 4;
    int wm = w / WNC, wn = w % WNC;
    int lr = lane >> 2, lb = lane & 3;
    int gblk = lb ^ ((lr >> 1) & 3);      // pre-swizzled global 16B-block
    const unsigned short* aSrc = A + (size_t)(m0 + w * AR + lr) * 1024 + gblk * 8;
    const unsigned short* bSrc = W + (size_t)(n0 + w * BR + lr) * 1024 + gblk * 8;
    int rc = (qd ^ ((l15 >> 1) & 3)) * 8; // swizzled frag col (shorts)
    int arow = (wm * 64 + l15) * 32 + rc;
    int brow = (wn * 64 + l15) * 32 + rc;

    auto stage = [&](int off, int kbv) {
        unsigned short* _sa = (unsigned short*)(smem + off);
        unsigned short* _sb = _sa + 128 * 32;
#pragma unroll
        for (int i = 0; i < AG; ++i)
            GLD16(aSrc + kbv + (size_t)i * 16 * 1024, _sa + (w * AR + i * 16) * 32);
#pragma unroll
        for (int i = 0; i < BG; ++i)
            GLD16(bSrc + kbv + (size_t)i * 16 * 1024, _sb + (w * BR + i * 16) * 32);
    };

    fx4 acc[4][4];
#pragma unroll
    for (int mt = 0; mt < 4; mt++)
#pragma unroll
        for (int nt = 0; nt < 4; nt++)
#pragma unroll
            for (int r = 0; r < 4; r++) acc[mt][nt][r] = 0.f;

    // prologue: tiles 0, 1
    stage(0, 0);
    stage(SLOT, 32);
    if constexpr (LPW == 3) asm volatile("s_waitcnt vmcnt(3)" ::: "memory");
    else                    asm volatile("s_waitcnt vmcnt(4)" ::: "memory");
    BARF();

    int oc = 0, on = SLOT, o2 = 2 * SLOT;
#pragma unroll 1
    for (int t = 0; t < 32; ++t) {
        if (t < 30) stage(o2, (t + 2) * 32);
        const unsigned short* cA = (const unsigned short*)(smem + oc);
        const unsigned short* cB = cA + 128 * 32;
        bh8 a[4], b[4];
#pragma unroll
        for (int mt = 0; mt < 4; ++mt) a[mt] = *(const bh8*)(cA + arow + mt * 512);
#pragma unroll
        for (int nt = 0; nt < 4; ++nt) b[nt] = *(const bh8*)(cB + brow + nt * 512);
        __builtin_amdgcn_s_setprio(1);
#pragma unroll
        for (int nt = 0; nt < 4; ++nt)
#pragma unroll
            for (int mt = 0; mt < 4; ++mt)
                acc[mt][nt] = __builtin_amdgcn_mfma_f32_16x16x32_bf16(a[mt], b[nt], acc[mt][nt], 0, 0, 0);
        __builtin_amdgcn_s_setprio(0);
        asm volatile("s_waitcnt lgkmcnt(0)" ::: "memory");
        if (t < 30) {
            if constexpr (LPW == 3) asm volatile("s_waitcnt vmcnt(3)" ::: "memory");
            else                    asm volatile("s_waitcnt vmcnt(4)" ::: "memory");
        } else if (t == 30) {
            asm volatile("s_waitcnt vmcnt(0)" ::: "memory");
        }
        BARF();
        int tmp = oc; oc = on; on = o2; o2 = tmp;
    }

    // ----- epilogues: per wave 64x64 at (m0 + wm*64, n0 + wn*64) -----
    int mb = m0 + wm * 64, nb = n0 + wn * 64;
    if (mode <= 1) {
#pragma unroll
        for (int mt = 0; mt < 4; mt++)
#pragma unroll
            for (int nt = 0; nt < 4; nt++)
#pragma unroll
                for (int r = 0; r < 4; r++) {
                    float v = acc[mt][nt][r];
                    if (mode == 1) v = v / (1.f + __expf(-v));
                    Cf[(size_t)(mb + mt * 16 + qd * 4 + r) * 1024 + nb + nt * 16 + l15] = v;
                }
    } else if (mode <= 3) {
        float s1 = (mode == 2) ? 1.f : -1.f;
#pragma unroll
        for (int mt = 0; mt < 4; mt++)
#pragma unroll
            for (int nt = 0; nt < 4; nt++)
#pragma unroll
                for (int r = 0; r < 4; r++) {
                    size_t idx = (size_t)(mb + mt * 16 + qd * 4 + r) * 1024 + nb + nt * 16 + l15;
                    float v = acc[mt][nt][r];
                    O1[idx] = f2bf(v * __expf(s1 * cfp[idx]));
                    O2[idx] = f2bf(v * __expf(-s1 * cbp[idx]));
                }
    } else {
        // V transpose: vvt[(b*1024 + d)][t]; T[BNv d][136] shorts
        unsigned short* T = (unsigned short*)smem;
        int bq = m0 >> 10, t0 = m0 & 1023;
#pragma unroll
        for (int mt = 0; mt < 4; mt++)
#pragma unroll
            for (int nt = 0; nt < 4; nt++) {
                int dl = wn * 64 + nt * 16 + l15;
                int tl = wm * 64 + mt * 16 + qd * 4;
                uint2 pk2;
                pk2.x = pkbf(acc[mt][nt][0], acc[mt][nt][1]);
                pk2.y = pkbf(acc[mt][nt][2], acc[mt][nt][3]);
                *(uint2*)(T + dl * 136 + tl) = pk2;
            }
        asm volatile("s_waitcnt lgkmcnt(0)" ::: "memory");
        BARF();
#pragma unroll
        for (int p = 0; p < 8; ++p) {
            int idx = p * (NW * 64) + tid;
            int dd = idx >> 4, u = idx & 15;
            uint4 vv = *(const uint4*)(T + dd * 136 + u * 8);
            *(uint4*)(O1 + (size_t)(bq * 1024 + n0 + dd) * 1024 + t0 + u * 8) = vv;
        }
    }
}

__global__ __launch_bounds__(512, 4) void k_qkvg(const unsigned short* __restrict__ xr16,
                                                 const unsigned short* __restrict__ xk16,
                                                 const unsigned short* __restrict__ xv16,
                                                 const unsigned short* __restrict__ xg16,
                                                 const unsigned short* __restrict__ Wrb,
                                                 const unsigned short* __restrict__ Wkb,
                                                 const unsigned short* __restrict__ Wvb,
                                                 const unsigned short* __restrict__ Wgb,
                                                 unsigned short* __restrict__ qf, unsigned short* __restrict__ qb,
                                                 unsigned short* __restrict__ kf, unsigned short* __restrict__ kb,
                                                 unsigned short* __restrict__ vvt,
                                                 float* __restrict__ gg,
                                                 const float* __restrict__ cf, const float* __restrict__ cb) {
    __shared__ __align__(16) char smem[73728];
    // bijective XCD swizzle (512 % 8 == 0): XCD x gets 64 contiguous work ids
    int flat = blockIdx.x;
    int wkid = (flat & 7) * 64 + (flat >> 3);
    int gy = wkid >> 7;                        // which GEMM (128 tiles each)
    int rem = wkid & 127;
    int m0 = (rem >> 2) * 128, n0 = (rem & 3) * 256;
    const unsigned short* Ap = (gy == 0) ? xr16 : (gy == 1) ? xk16 : (gy == 2) ? xv16 : xg16;
    const unsigned short* Wp = (gy == 0) ? Wrb : (gy == 1) ? Wkb : (gy == 2) ? Wvb : Wgb;
    int mode = (gy == 0) ? 2 : (gy == 1) ? 3 : (gy == 2) ? 4 : 1;
    unsigned short* o1 = (gy == 0) ? qf : (gy == 1) ? kf : (gy == 2) ? vvt : nullptr;
    unsigned short* o2 = (gy == 0) ? qb : (gy == 1) ? kb : nullptr;
    float* cfo = (gy == 3) ? gg : nullptr;
    gemm_v5<8, 256>(Ap, Wp, m0, n0, mode, cfo, o1, o2, cf, cb, smem);
}

__global__ __launch_bounds__(256, 3) void k_gemmo(const unsigned short* __restrict__ z16,
                                                  const unsigned short* __restrict__ Wob,
                                                  float* __restrict__ out) {
    __shared__ __align__(16) char smem[49152];
    int flat = blockIdx.x;                     // grid 256 (256 % 8 == 0)
    int wkid = (flat & 7) * 32 + (flat >> 3);
    int m0 = (wkid >> 3) * 128, n0 = (wkid & 7) * 128;
    gemm_v5<4, 128>(z16, Wob, m0, n0, 0, out, nullptr, nullptr, nullptr, nullptr, smem);
}

// ---------- attention v2: bidir LION, barrier-free, direct-L2 fragment loads ----------
// Working set per (XCD, phase) ~3MB (8 bh x {K,V,Q} panels) fits the 4MB per-XCD L2
// (catalog m169: LDS-staging L2-resident data is pure overhead). Each lane loads its
// MFMA fragments straight from global; no LDS, no __syncthreads, per-wave j-ranges,
// setprio around MFMA clusters (m191 regime: independent waves).
__global__ __launch_bounds__(256) void k_attn(const unsigned short* __restrict__ qf,
                                              const unsigned short* __restrict__ qb,
                                              const unsigned short* __restrict__ kf,
                                              const unsigned short* __restrict__ kb,
                                              const unsigned short* __restrict__ vvt,
                                              float* __restrict__ y) {
    int tid = threadIdx.x;
    int w = tid >> 6, lane = tid & 63, l15 = lane & 15, qd = lane >> 4;
    int bid = blockIdx.x;            // grid 512 = 64 bh x 8 itile, XCD-swizzled
    int bh = (bid & 7) + ((bid >> 6) << 3);
    int ib = (bid >> 3) & 7;
    int b = bh >> 4, h = bh & 15;
    int i0w = ib * 128 + w * 32;
    int bt0 = b * 1024;
    int fmax = (i0w + 31) >> 6;       // last forward chunk this wave computes
    int bmin = i0w >> 6;              // first backward chunk this wave computes
    int srcA = l15 + ((lane & 16) << 1);
    int srcB = srcA + 16;
    // V fragment base: row (b*1024 + h*64 + mt*16 + l15), col jb + ks2*32 + qd*8
    const unsigned short* vB = vvt + (size_t)(b * 1024 + h * 64 + l15) * 1024 + qd * 8;
    fx4 yacc[4][2];
#pragma unroll
    for (int mt = 0; mt < 4; mt++)
#pragma unroll
        for (int nt = 0; nt < 2; nt++)
#pragma unroll
            for (int r = 0; r < 4; r++) yacc[mt][nt][r] = 0.f;

    for (int phase = 0; phase < 2; phase++) {
        const unsigned short* Q = phase ? qb : qf;
        const unsigned short* K = phase ? kb : kf;
        bh8 qfr[2][2];
#pragma unroll
        for (int nt = 0; nt < 2; nt++)
#pragma unroll
            for (int ks = 0; ks < 2; ks++)
                qfr[nt][ks] = *(const bh8*)(Q + (size_t)(bt0 + i0w + nt * 16 + l15) * 1024
                                              + h * 64 + ks * 32 + qd * 8);
        // K fragment base: row (bt0 + jb + mt*16 + l15), col h*64 + ks*32 + qd*8
        const unsigned short* kB = K + (size_t)(bt0 + l15) * 1024 + h * 64 + qd * 8;
        int lo = phase == 0 ? 0 : bmin;
        int hi = phase == 0 ? fmax : 15;
        for (int jt = lo; jt <= hi; jt++) {
            int jb = jt * 64;
            bool needmask = (phase == 0) ? (jb + 63 > i0w) : (i0w + 31 >= jb);
            // direct K fragment loads (L2-resident)
            bh8 kc[8];
#pragma unroll
            for (int ks = 0; ks < 2; ks++)
#pragma unroll
                for (int mt = 0; mt < 4; mt++)
                    kc[ks * 4 + mt] = *(const bh8*)(kB + (size_t)(jb + mt * 16) * 1024 + ks * 32);
            // QK: S^T tile (64j x 32i)
            fx4 sacc[4][2];
#pragma unroll
            for (int mt = 0; mt < 4; mt++)
#pragma unroll
                for (int nt = 0; nt < 2; nt++)
#pragma unroll
                    for (int r = 0; r < 4; r++) sacc[mt][nt][r] = 0.f;
            __builtin_amdgcn_s_setprio(1);
#pragma unroll
            for (int ks = 0; ks < 2; ks++)
#pragma unroll
                for (int mt = 0; mt < 4; mt++)
#pragma unroll
                    for (int nt = 0; nt < 2; nt++)
                        sacc[mt][nt] = __builtin_amdgcn_mfma_f32_16x16x32_bf16(kc[ks * 4 + mt], qfr[nt][ks], sacc[mt][nt], 0, 0, 0);
            __builtin_amdgcn_s_setprio(0);
            // direct V fragment loads (issued under mask/pack VALU)
            bh8 vc[8];
#pragma unroll
            for (int ks2 = 0; ks2 < 2; ks2++)
#pragma unroll
                for (int mt = 0; mt < 4; mt++)
                    vc[ks2 * 4 + mt] = *(const bh8*)(vB + (size_t)(mt * 16) * 1024 + jb + ks2 * 32);
            // mask + pack bf16
            uint2 pk[4][2];
#pragma unroll
            for (int mt = 0; mt < 4; mt++)
#pragma unroll
                for (int nt = 0; nt < 2; nt++) {
                    fx4 s = sacc[mt][nt];
                    if (needmask) {
                        int ii = i0w + nt * 16 + l15;
                        int jj0 = jb + mt * 16 + qd * 4;
#pragma unroll
                        for (int r = 0; r < 4; r++) {
                            bool keep = (phase == 0) ? (ii >= jj0 + r) : (ii < jj0 + r);
                            if (!keep) s[r] = 0.f;
                        }
                    }
                    pk[mt][nt].x = pkbf(s[0], s[1]);
                    pk[mt][nt].y = pkbf(s[2], s[3]);
                }
            // y^T += V^T * S^T : B = S^T frag via shfl redistribution
#pragma unroll
            for (int ks2 = 0; ks2 < 2; ks2++) {
#pragma unroll
                for (int nt = 0; nt < 2; nt++) {
                    int lox  = __shfl((int)pk[2 * ks2][nt].x,     srcA);
                    int hix  = __shfl((int)pk[2 * ks2 + 1][nt].x, srcA);
                    int loy  = __shfl((int)pk[2 * ks2][nt].y,     srcA);
                    int hiy  = __shfl((int)pk[2 * ks2 + 1][nt].y, srcA);
                    int lox2 = __shfl((int)pk[2 * ks2][nt].x,     srcB);
                    int hix2 = __shfl((int)pk[2 * ks2 + 1][nt].x, srcB);
                    int loy2 = __shfl((int)pk[2 * ks2][nt].y,     srcB);
                    int hiy2 = __shfl((int)pk[2 * ks2 + 1][nt].y, srcB);
                    union { int4 i; bh8 h; } cv;
                    cv.i.x = (qd & 2) ? hix  : lox;
                    cv.i.y = (qd & 2) ? hiy  : loy;
                    cv.i.z = (qd & 2) ? hix2 : lox2;
                    cv.i.w = (qd & 2) ? hiy2 : loy2;
                    __builtin_amdgcn_s_setprio(1);
#pragma unroll
                    for (int mt = 0; mt < 4; mt++)
                        yacc[mt][nt] = __builtin_amdgcn_mfma_f32_16x16x32_bf16(vc[ks2 * 4 + mt], cv.h, yacc[mt][nt], 0, 0, 0);
                    __builtin_amdgcn_s_setprio(0);
                }
            }
        }
    }
    // store y^T C-frags: i = col, d = row -> float4 along d
#pragma unroll
    for (int mt = 0; mt < 4; mt++)
#pragma unroll
        for (int nt = 0; nt < 2; nt++) {
            fx4 s = yacc[mt][nt];
            float4 o; o.x = s[0]; o.y = s[1]; o.z = s[2]; o.w = s[3];
            *(float4*)&y[(size_t)(bt0 + i0w + nt * 16 + l15) * 1024 + h * 64 + mt * 16 + qd * 4] = o;
        }
}

// ---------- groupnorm * g -> bf16 z ----------
__global__ __launch_bounds__(256) void k_gn(const float* __restrict__ y,
                                            const float* __restrict__ g,
                                            const float* __restrict__ lnw,
                                            const float* __restrict__ lnb,
                                            unsigned short* __restrict__ z16) {
    int tid = threadIdx.x;
    int lane = tid & 63;
    int wv = tid >> 6;
    int group = blockIdx.x * 4 + wv;     // grid 16384
    int tok = group >> 4, h = group & 15;
    int d = h * 64 + lane;
    size_t idx = (size_t)tok * 1024 + d;
    float val = y[idx];
    float s = val, s2 = val * val;
#pragma unroll
    for (int off = 32; off > 0; off >>= 1) {
        s  += __shfl_xor(s, off, 64);
        s2 += __shfl_xor(s2, off, 64);
    }
    float mu = s * (1.f / 64.f);
    float var = s2 * (1.f / 64.f) - mu * mu;
    float inv = rsqrtf(var + 6.4e-4f);
    float yn = (val - mu) * inv * lnw[d] + lnb[d];
    z16[idx] = f2bf(yn * g[idx]);
}

extern "C" void kernel_launch(void* const* d_in, const int* in_sizes, int n_in,
                              void* d_out, int out_size, void* d_ws, size_t ws_size,
                              hipStream_t stream) {
    const float* x     = (const float*)d_in[0];
    const float* maa_x = (const float*)d_in[1];
    const float* maa_w = (const float*)d_in[2];
    const float* maa_k = (const float*)d_in[3];
    const float* maa_v = (const float*)d_in[4];
    const float* maa_r = (const float*)d_in[5];
    const float* maa_g = (const float*)d_in[6];
    const float* w1    = (const float*)d_in[7];
    const float* w2    = (const float*)d_in[8];
    const float* tdec  = (const float*)d_in[9];
    const float* dw1   = (const float*)d_in[10];
    const float* dw2   = (const float*)d_in[11];
    const float* W_r   = (const float*)d_in[12];
    const float* W_k   = (const float*)d_in[13];
    const float* W_v   = (const float*)d_in[14];
    const float* W_g   = (const float*)d_in[15];
    const float* W_o   = (const float*)d_in[16];
    const float* lnw   = (const float*)d_in[17];
    const float* lnb   = (const float*)d_in[18];

    float* ws = (float*)d_ws;
    size_t o = 0;
    float* dech   = ws + o; o += 262144;
    float* segsum = ws + o; o += 131072;
    float* ew     = ws + o; o += 4194304;
    float* cf     = ws + o; o += 4194304;
    float* cb     = ws + o; o += 4194304;
    float* gg     = ws + o; o += 4194304;
    unsigned short* us = (unsigned short*)(ws + o);
    size_t u = 0;
    unsigned short* xmix16 = us + u; u += 4194304;
    unsigned short* xw16 = us + u; u += 4194304;
    unsigned short* xr16 = us + u; u += 4194304;   // also z16 after gemm4
    unsigned short* xk16 = us + u; u += 4194304;
    unsigned short* xv16 = us + u; u += 4194304;
    unsigned short* xg16 = us + u; u += 4194304;
    unsigned short* qf   = us + u; u += 4194304;
    unsigned short* qb   = us + u; u += 4194304;
    unsigned short* kf   = us + u; u += 4194304;
    unsigned short* kb   = us + u; u += 4194304;
    unsigned short* vvt  = us + u; u += 4194304;
    unsigned short* Wrb  = us + u; u += 1048576;
    unsigned short* Wkb  = us + u; u += 1048576;
    unsigned short* Wvb  = us + u; u += 1048576;
    unsigned short* Wgb  = us + u; u += 1048576;
    unsigned short* Wob  = us + u; u += 1048576;
    unsigned short* w1T  = us + u; u += 163840;
    unsigned short* dw1T = us + u; u += 65536;
    unsigned short* xxx16 = us + u; u += 655360;
    unsigned short* w2T16 = us + u; u += 163840;
    float* yb0 = cf;               // attention output reuses cf (dead after gemm4)
    unsigned short* z16 = xr16;    // dead after gemm4

    k_prep<<<dim3(640, 7), 256, 0, stream>>>(W_r, W_k, W_v, W_g, W_o, w1, dw1, w2,
                                             Wrb, Wkb, Wvb, Wgb, Wob, w1T, dw1T, w2T16);
    k_mixx<<<4096, 256, 0, stream>>>(x, maa_x, xmix16);
    k_xxx2<<<256, 256, 0, stream>>>(xmix16, w1T, xxx16);
    k_mmix<<<dim3(16, 32), 256, 0, stream>>>(x, xxx16, w2T16, maa_w, maa_k, maa_v, maa_r, maa_g,
                                             xw16, xk16, xv16, xr16, xg16);
    k_dec1m<<<256, 256, 0, stream>>>(xw16, dw1T, dech);
    k_dec2<<<512, 256, 0, stream>>>(dech, dw2, tdec, ew);
    k_scan1<<<2048, 64, 0, stream>>>(ew, segsum);
    k_scan3<<<2048, 64, 0, stream>>>(ew, segsum, cf, cb);
    k_qkvg<<<dim3(512), dim3(512), 0, stream>>>(xr16, xk16, xv16, xg16, Wrb, Wkb, Wvb, Wgb,
                                                qf, qb, kf, kb, vvt, gg, cf, cb);
    k_attn<<<512, 256, 0, stream>>>(qf, qb, kf, kb, vvt, yb0);
    k_gn<<<16384, 256, 0, stream>>>(yb0, gg, lnw, lnb, z16);
    k_gemmo<<<256, 256, 0, stream>>>(z16, Wob, (float*)d_out);
}

// Round 10
// 326.554 us; speedup vs baseline: 1.0899x; 1.0899x over previous
//
#include <hip/hip_runtime.h>
#include <math.h>

#define NB 4
#define TT 1024
#define DD 1024
#define NTOK 4096
#define ND (NTOK*DD)

typedef __attribute__((ext_vector_type(8))) short bh8;
typedef __attribute__((ext_vector_type(4))) float fx4;

__device__ __forceinline__ unsigned short f2bf(float f) {
    unsigned int b = __float_as_uint(f);
    b += 0x7fffu + ((b >> 16) & 1u);
    return (unsigned short)(b >> 16);
}

// pack two fp32 -> packed bf16 (RNE); HW v_cvt_pk_bf16_f32 when available
__device__ __forceinline__ unsigned pkbf(float a, float b) {
#if __has_builtin(__builtin_amdgcn_cvt_pk_bf16_f32)
    auto r = __builtin_amdgcn_cvt_pk_bf16_f32(a, b);
    unsigned u;
    __builtin_memcpy(&u, &r, 4);
    return u;
#else
    return ((unsigned)f2bf(b) << 16) | f2bf(a);
#endif
}

// async global->LDS, 16B per lane, LDS dst = wave-uniform base + lane*16
#define GLD16(gp, lp) __builtin_amdgcn_global_load_lds( \
    (__attribute__((address_space(1))) void*)(gp), \
    (__attribute__((address_space(3))) void*)(lp), 16, 0, 0)

// barrier that is also a compiler memory fence
#define BARF() do { __builtin_amdgcn_s_barrier(); asm volatile("" ::: "memory"); } while (0)

// ---------- fused preprocessing: 5x wconv, w1T, dw1T, w2T ----------
__global__ __launch_bounds__(256) void k_prep(const float* __restrict__ W_r, const float* __restrict__ W_k,
                                              const float* __restrict__ W_v, const float* __restrict__ W_g,
                                              const float* __restrict__ W_o,
                                              const float* __restrict__ w1, const float* __restrict__ dw1,
                                              const float* __restrict__ w2,
                                              unsigned short* __restrict__ Wrb, unsigned short* __restrict__ Wkb,
                                              unsigned short* __restrict__ Wvb, unsigned short* __restrict__ Wgb,
                                              unsigned short* __restrict__ Wob,
                                              unsigned short* __restrict__ w1T, unsigned short* __restrict__ dw1T,
                                              unsigned short* __restrict__ w2T16) {
    int y = blockIdx.y, bx = blockIdx.x, tid = threadIdx.x;   // grid (640, 7)
    if (y < 5) {
        if (bx >= 512) return;
        const float* s = (y == 0) ? W_r : (y == 1) ? W_k : (y == 2) ? W_v : (y == 3) ? W_g : W_o;
        unsigned short* d = (y == 0) ? Wrb : (y == 1) ? Wkb : (y == 2) ? Wvb : (y == 3) ? Wgb : Wob;
        int i = (bx * 256 + tid) * 8;
        float4 a = *(const float4*)(s + i);
        float4 b = *(const float4*)(s + i + 4);
        uint4 o;
        o.x = pkbf(a.x, a.y);
        o.y = pkbf(a.z, a.w);
        o.z = pkbf(b.x, b.y);
        o.w = pkbf(b.z, b.w);
        *(uint4*)(d + i) = o;
    } else if (y == 5) {
        int o = bx * 256 + tid;          // 163840 total
        int r = o & 1023, c = o >> 10;
        w1T[o] = f2bf(w1[r * 160 + c]);
    } else {
        if (bx < 256) {
            int o = bx * 256 + tid;      // 65536 total
            int r = o & 1023, c = o >> 10;
            dw1T[o] = f2bf(dw1[r * 64 + c]);
        } else if (bx < 276) {
            int wi = bx - 256;
            int f = wi >> 2;
            int d = (wi & 3) * 256 + tid;
#pragma unroll 8
            for (int m = 0; m < 32; m++)
                w2T16[(size_t)(f * 1024 + d) * 32 + m] = f2bf(w2[(size_t)(f * 32 + m) * 1024 + d]);
        }
    }
}

// ---------- k1: xmix16 = bf16(x + dxprev * maa_x) ----------
__global__ __launch_bounds__(256) void k_mixx(const float* __restrict__ x,
                                              const float* __restrict__ maa_x,
                                              unsigned short* __restrict__ xmix16) {
    int base = (blockIdx.x * 256 + threadIdx.x) * 4;   // grid 4096
    int t = (base >> 10) & 1023;
    int d = base & 1023;
    float4 xv = *(const float4*)(x + base);
    float4 xm = (t > 0)    ? *(const float4*)(x + base - 1024) : make_float4(0, 0, 0, 0);
    float4 xp = (t < 1023) ? *(const float4*)(x + base + 1024) : make_float4(0, 0, 0, 0);
    float4 ma = *(const float4*)(maa_x + d);
    uint2 o;
    float a0 = xv.x + (0.5f * (xm.x + xp.x) - xv.x) * ma.x;
    float a1 = xv.y + (0.5f * (xm.y + xp.y) - xv.y) * ma.y;
    float a2 = xv.z + (0.5f * (xm.z + xp.z) - xv.z) * ma.z;
    float a3 = xv.w + (0.5f * (xm.w + xp.w) - xv.w) * ma.w;
    o.x = pkbf(a0, a1);
    o.y = pkbf(a2, a3);
    *(uint2*)(xmix16 + base) = o;
}

// ---------- k2: xxx16 = bf16(tanh(xmix @ w1)), 4-wave K-split ----------
__global__ __launch_bounds__(256) void k_xxx2(const unsigned short* __restrict__ xmix16,
                                              const unsigned short* __restrict__ w1T,
                                              unsigned short* __restrict__ xxx16) {
    __shared__ __align__(16) float red[4][10][64][4];   // 40 KB
    int tid = threadIdx.x;
    int lane = tid & 63, wv = tid >> 6;
    int l15 = lane & 15, qd = lane >> 4;
    int m0 = blockIdx.x * 16;    // grid 256
    fx4 acc[10];
#pragma unroll
    for (int nt = 0; nt < 10; nt++)
#pragma unroll
        for (int r = 0; r < 4; r++) acc[nt][r] = 0.f;
    int kb0 = wv * 256;
#pragma unroll 2
    for (int kb = kb0; kb < kb0 + 256; kb += 32) {
        bh8 af = *(const bh8*)(xmix16 + (size_t)(m0 + l15) * 1024 + kb + qd * 8);
#pragma unroll
        for (int nt = 0; nt < 10; nt++) {
            bh8 bf = *(const bh8*)(w1T + (size_t)(nt * 16 + l15) * 1024 + kb + qd * 8);
            acc[nt] = __builtin_amdgcn_mfma_f32_16x16x32_bf16(af, bf, acc[nt], 0, 0, 0);
        }
    }
#pragma unroll
    for (int nt = 0; nt < 10; nt++)
        *(fx4*)&red[wv][nt][lane][0] = acc[nt];
    __syncthreads();
    if (wv == 0) {
#pragma unroll
        for (int nt = 0; nt < 10; nt++) {
            fx4 s = *(const fx4*)&red[0][nt][lane][0];
            s = s + *(const fx4*)&red[1][nt][lane][0];
            s = s + *(const fx4*)&red[2][nt][lane][0];
            s = s + *(const fx4*)&red[3][nt][lane][0];
#pragma unroll
            for (int r = 0; r < 4; r++)
                xxx16[(size_t)(m0 + qd * 4 + r) * 160 + nt * 16 + l15] = f2bf(tanhf(s[r]));
        }
    }
}

// ---------- k3: fused mm-einsum (MFMA, K=32) + five mixes, no LDS ----------
__global__ __launch_bounds__(256, 2) void k_mmix(const float* __restrict__ x,
                                                 const unsigned short* __restrict__ xxx16,
                                                 const unsigned short* __restrict__ w2T16,
                                                 const float* __restrict__ maa_w,
                                                 const float* __restrict__ maa_k,
                                                 const float* __restrict__ maa_v,
                                                 const float* __restrict__ maa_r,
                                                 const float* __restrict__ maa_g,
                                                 unsigned short* __restrict__ xw16,
                                                 unsigned short* __restrict__ xk16,
                                                 unsigned short* __restrict__ xv16,
                                                 unsigned short* __restrict__ xr16,
                                                 unsigned short* __restrict__ xg16) {
    int tid = threadIdx.x;
    int w = tid >> 6, lane = tid & 63, l15 = lane & 15, qd = lane >> 4;
    int n0 = blockIdx.x * 64;               // grid (16, 32)
    int m0w = blockIdx.y * 128 + w * 32;
    const float* maap[5] = {maa_w, maa_k, maa_v, maa_r, maa_g};
    unsigned short* outp[5] = {xw16, xk16, xv16, xr16, xg16};
    float xin[8][4], dxv[8][4];
#pragma unroll
    for (int mi = 0; mi < 2; mi++)
#pragma unroll
        for (int r = 0; r < 4; r++) {
            int tok = m0w + mi * 16 + qd * 4 + r;
            int t = tok & 1023;
#pragma unroll
            for (int ni = 0; ni < 4; ni++) {
                int d = n0 + ni * 16 + l15;
                size_t idx = (size_t)tok * 1024 + d;
                float xv = x[idx];
                float xm1 = (t > 0)    ? x[idx - 1024] : 0.f;
                float xp1 = (t < 1023) ? x[idx + 1024] : 0.f;
                xin[mi * 4 + r][ni] = xv;
                dxv[mi * 4 + r][ni] = 0.5f * (xm1 + xp1) - xv;
            }
        }
#pragma unroll
    for (int f = 0; f < 5; f++) {
        bh8 af[2], bf[4];
#pragma unroll
        for (int mi = 0; mi < 2; mi++)
            af[mi] = *(const bh8*)(xxx16 + (size_t)(m0w + mi * 16 + l15) * 160 + f * 32 + qd * 8);
#pragma unroll
        for (int ni = 0; ni < 4; ni++)
            bf[ni] = *(const bh8*)(w2T16 + (size_t)(f * 1024 + n0 + ni * 16 + l15) * 32 + qd * 8);
        fx4 acc[2][4];
#pragma unroll
        for (int mi = 0; mi < 2; mi++)
#pragma unroll
            for (int ni = 0; ni < 4; ni++) {
#pragma unroll
                for (int r = 0; r < 4; r++) acc[mi][ni][r] = 0.f;
                acc[mi][ni] = __builtin_amdgcn_mfma_f32_16x16x32_bf16(af[mi], bf[ni], acc[mi][ni], 0, 0, 0);
            }
        const float* maa = maap[f];
        unsigned short* op = outp[f];
#pragma unroll
        for (int ni = 0; ni < 4; ni++) {
            float mv = maa[n0 + ni * 16 + l15];
#pragma unroll
            for (int mi = 0; mi < 2; mi++)
#pragma unroll
                for (int r = 0; r < 4; r++) {
                    float o = xin[mi * 4 + r][ni] + dxv[mi * 4 + r][ni] * (mv + acc[mi][ni][r]);
                    op[(size_t)(m0w + mi * 16 + qd * 4 + r) * 1024 + n0 + ni * 16 + l15] = f2bf(o);
                }
        }
    }
}

// ---------- decay GEMM1: dech = tanh(xw @ dw1), 4-wave K-split ----------
__global__ __launch_bounds__(256) void k_dec1m(const unsigned short* __restrict__ xw16,
                                               const unsigned short* __restrict__ dw1T,
                                               float* __restrict__ dech) {
    __shared__ __align__(16) float red[4][4][64][4];    // 16 KB
    int tid = threadIdx.x;
    int lane = tid & 63, wv = tid >> 6;
    int l15 = lane & 15, qd = lane >> 4;
    int m0 = blockIdx.x * 16;    // grid 256
    fx4 acc[4];
#pragma unroll
    for (int nt = 0; nt < 4; nt++)
#pragma unroll
        for (int r = 0; r < 4; r++) acc[nt][r] = 0.f;
    int kb0 = wv * 256;
#pragma unroll 2
    for (int kb = kb0; kb < kb0 + 256; kb += 32) {
        bh8 af = *(const bh8*)(xw16 + (size_t)(m0 + l15) * 1024 + kb + qd * 8);
#pragma unroll
        for (int nt = 0; nt < 4; nt++) {
            bh8 bf = *(const bh8*)(dw1T + (size_t)(nt * 16 + l15) * 1024 + kb + qd * 8);
            acc[nt] = __builtin_amdgcn_mfma_f32_16x16x32_bf16(af, bf, acc[nt], 0, 0, 0);
        }
    }
#pragma unroll
    for (int nt = 0; nt < 4; nt++)
        *(fx4*)&red[wv][nt][lane][0] = acc[nt];
    __syncthreads();
    if (wv == 0) {
#pragma unroll
        for (int nt = 0; nt < 4; nt++) {
            fx4 s = *(const fx4*)&red[0][nt][lane][0];
            s = s + *(const fx4*)&red[1][nt][lane][0];
            s = s + *(const fx4*)&red[2][nt][lane][0];
            s = s + *(const fx4*)&red[3][nt][lane][0];
#pragma unroll
            for (int r = 0; r < 4; r++)
                dech[(size_t)(m0 + qd * 4 + r) * 64 + nt * 16 + l15] = tanhf(s[r]);
        }
    }
}

// ---------- decay GEMM2: ew = -exp(time_decay + dech @ dw2) ----------
__global__ __launch_bounds__(256) void k_dec2(const float* __restrict__ dech,
                                              const float* __restrict__ dw2,
                                              const float* __restrict__ tdec,
                                              float* __restrict__ ew) {
    __shared__ float hl[8][64];
    int tid = threadIdx.x;
    int tok0 = blockIdx.x * 8;     // grid 512
    {
        int l = tid;        hl[l >> 6][l & 63] = dech[tok0 * 64 + l];
        l = tid + 256;      hl[l >> 6][l & 63] = dech[tok0 * 64 + l];
    }
    __syncthreads();
#pragma unroll 1
    for (int c = 0; c < 4; c++) {
        int d = c * 256 + tid;
        float acc[8] = {};
#pragma unroll 8
        for (int j = 0; j < 64; j++) {
            float wv = dw2[j * 1024 + d];
#pragma unroll
            for (int g = 0; g < 8; g++) acc[g] = fmaf(hl[g][j], wv, acc[g]);
        }
        float td = tdec[d];
#pragma unroll
        for (int g = 0; g < 8; g++) ew[(tok0 + g) * 1024 + d] = -expf(td + acc[g]);
    }
}

// ---------- scan stage 1: per-segment sums (seg = 32) ----------
__global__ __launch_bounds__(64) void k_scan1(const float* __restrict__ ew, float* __restrict__ segsum) {
    int bx = blockIdx.x;            // grid 2048 = 4b x 32seg x 16dch
    int b = bx >> 9, seg = (bx >> 4) & 31, dch = bx & 15;
    int d = dch * 64 + threadIdx.x;
    size_t base = ((size_t)(b * 1024 + seg * 32)) * 1024 + d;
    float s = 0.f;
#pragma unroll 8
    for (int t = 0; t < 32; t++) s += ew[base + (size_t)t * 1024];
    segsum[(b * 32 + seg) * 1024 + d] = s;
}

// ---------- scan stage 2+3 fused: local prefix of segsums + emit clipped cf/cb ----------
__global__ __launch_bounds__(64) void k_scan3(const float* __restrict__ ew, const float* __restrict__ segsum,
                                              float* __restrict__ cf, float* __restrict__ cb) {
    int bx = blockIdx.x;            // grid 2048
    int b = bx >> 9, seg = (bx >> 4) & 31, dch = bx & 15;
    int d = dch * 64 + threadIdx.x;
    float run = 0.f, pre = 0.f, off16 = 0.f;
#pragma unroll
    for (int s = 0; s < 32; s++) {
        float tv = segsum[(b * 32 + s) * 1024 + d];
        if (s == seg) pre = run;
        if (s == 16) off16 = run;
        run += tv;
    }
    float e512 = ew[((size_t)(b * 1024 + 512)) * 1024 + d];
    float sb = off16;           // cs[511]
    float sf = off16 + e512;    // cs[512]
    float cum = pre;
    size_t base = ((size_t)(b * 1024 + seg * 32)) * 1024 + d;
#pragma unroll 4
    for (int t = 0; t < 32; t++) {
        float prev = cum;
        cum += ew[base + (size_t)t * 1024];
        cf[base + (size_t)t * 1024] = fminf(fmaxf(cum - sf, -60.f), 60.f);
        cb[base + (size_t)t * 1024] = fminf(fmaxf(prev - sb, -60.f), 60.f);
    }
}

// ---------- GEMM engine v5: occupancy-first. BM=128, BN templated, BK=32 ----------
// Wide  (NW=8, BN=256): 512 thr, wave 64x64 (64 AGPR), regs forced <=128 by
//   __launch_bounds__(512,4); LDS ring-3 x 24KB = 72KB -> 2 blocks x 8 waves
//   = 16 waves/CU (4/SIMD). Per wave/tile: 16 MFMA, 8 b128, 3 GLD16 -> vmcnt(3).
// Narrow (NW=4, BN=128): 256 thr, ring-3 x 16KB = 48KB -> 3 blocks/CU (12 waves).
// Zero-conflict swizzle proven in r4: stage gblk = lb ^ ((lr>>1)&3),
// read col qd ^ ((l15>>1)&3). One barrier/tile, counted vmcnt (never 0 till tail).
// modes: 0 fp32 out, 1 silu fp32, 2 q-exp (O1=qf,O2=qb), 3 k-exp, 4 v-transpose (O1=vvt)
template<int NW, int BNv>
__device__ __forceinline__ void gemm_v5(const unsigned short* __restrict__ A,
                                        const unsigned short* __restrict__ W,
                                        int m0, int n0, int mode,
                                        float* __restrict__ Cf,
                                        unsigned short* __restrict__ O1,
                                        unsigned short* __restrict__ O2,
                                        const float* __restrict__ cfp,
                                        const float* __restrict__ cbp,
                                        char* smem) {
    constexpr int AR = 128 / NW;          // A rows staged per wave
    constexpr int AG = AR / 16;           // GLD16s for A per wave
    constexpr int BR = BNv / NW;          // B rows per wave
    constexpr int BG = BR / 16;
    constexpr int LPW = AG + BG;          // loads per wave per tile
    constexpr int SLOT = (128 + BNv) * 64;   // ring slot bytes
    constexpr int WNC = BNv / 64;

    int tid = threadIdx.x;
    int lane = tid & 63, w = tid >> 6;
    int l15 = lane & 15, qd = lane >> 4;
    int wm = w / WNC, wn = w % WNC;
    int lr = lane >> 2, lb = lane & 3;
    int gblk = lb ^ ((lr >> 1) & 3);      // pre-swizzled global 16B-block
    const unsigned short* aSrc = A + (size_t)(m0 + w * AR + lr) * 1024 + gblk * 8;
    const unsigned short* bSrc = W + (size_t)(n0 + w * BR + lr) * 1024 + gblk * 8;
    int rc = (qd ^ ((l15 >> 1) & 3)) * 8; // swizzled frag col (shorts)
    int arow = (wm * 64 + l15) * 32 + rc;
    int brow = (wn * 64 + l15) * 32 + rc;

    auto stage = [&](int off, int kbv) {
        unsigned short* _sa = (unsigned short*)(smem + off);
        unsigned short* _sb = _sa + 128 * 32;
#pragma unroll
        for (int i = 0; i < AG; ++i)
            GLD16(aSrc + kbv + (size_t)i * 16 * 1024, _sa + (w * AR + i * 16) * 32);
#pragma unroll
        for (int i = 0; i < BG; ++i)
            GLD16(bSrc + kbv + (size_t)i * 16 * 1024, _sb + (w * BR + i * 16) * 32);
    };

    fx4 acc[4][4];
#pragma unroll
    for (int mt = 0; mt < 4; mt++)
#pragma unroll
        for (int nt = 0; nt < 4; nt++)
#pragma unroll
            for (int r = 0; r < 4; r++) acc[mt][nt][r] = 0.f;

    // prologue: tiles 0, 1
    stage(0, 0);
    stage(SLOT, 32);
    if constexpr (LPW == 3) asm volatile("s_waitcnt vmcnt(3)" ::: "memory");
    else                    asm volatile("s_waitcnt vmcnt(4)" ::: "memory");
    BARF();

    int oc = 0, on = SLOT, o2 = 2 * SLOT;
#pragma unroll 1
    for (int t = 0; t < 32; ++t) {
        if (t < 30) stage(o2, (t + 2) * 32);
        const unsigned short* cA = (const unsigned short*)(smem + oc);
        const unsigned short* cB = cA + 128 * 32;
        bh8 a[4], b[4];
#pragma unroll
        for (int mt = 0; mt < 4; ++mt) a[mt] = *(const bh8*)(cA + arow + mt * 512);
#pragma unroll
        for (int nt = 0; nt < 4; ++nt) b[nt] = *(const bh8*)(cB + brow + nt * 512);
        __builtin_amdgcn_s_setprio(1);
#pragma unroll
        for (int nt = 0; nt < 4; ++nt)
#pragma unroll
            for (int mt = 0; mt < 4; ++mt)
                acc[mt][nt] = __builtin_amdgcn_mfma_f32_16x16x32_bf16(a[mt], b[nt], acc[mt][nt], 0, 0, 0);
        __builtin_amdgcn_s_setprio(0);
        asm volatile("s_waitcnt lgkmcnt(0)" ::: "memory");
        if (t < 30) {
            if constexpr (LPW == 3) asm volatile("s_waitcnt vmcnt(3)" ::: "memory");
            else                    asm volatile("s_waitcnt vmcnt(4)" ::: "memory");
        } else if (t == 30) {
            asm volatile("s_waitcnt vmcnt(0)" ::: "memory");
        }
        BARF();
        int tmp = oc; oc = on; on = o2; o2 = tmp;
    }

    // ----- epilogues: per wave 64x64 at (m0 + wm*64, n0 + wn*64) -----
    int mb = m0 + wm * 64, nb = n0 + wn * 64;
    if (mode <= 1) {
#pragma unroll
        for (int mt = 0; mt < 4; mt++)
#pragma unroll
            for (int nt = 0; nt < 4; nt++)
#pragma unroll
                for (int r = 0; r < 4; r++) {
                    float v = acc[mt][nt][r];
                    if (mode == 1) v = v / (1.f + __expf(-v));
                    Cf[(size_t)(mb + mt * 16 + qd * 4 + r) * 1024 + nb + nt * 16 + l15] = v;
                }
    } else if (mode <= 3) {
        float s1 = (mode == 2) ? 1.f : -1.f;
#pragma unroll
        for (int mt = 0; mt < 4; mt++)
#pragma unroll
            for (int nt = 0; nt < 4; nt++)
#pragma unroll
                for (int r = 0; r < 4; r++) {
                    size_t idx = (size_t)(mb + mt * 16 + qd * 4 + r) * 1024 + nb + nt * 16 + l15;
                    float v = acc[mt][nt][r];
                    O1[idx] = f2bf(v * __expf(s1 * cfp[idx]));
                    O2[idx] = f2bf(v * __expf(-s1 * cbp[idx]));
                }
    } else {
        // V transpose: vvt[(b*1024 + d)][t]; T[BNv d][136] shorts
        unsigned short* T = (unsigned short*)smem;
        int bq = m0 >> 10, t0 = m0 & 1023;
#pragma unroll
        for (int mt = 0; mt < 4; mt++)
#pragma unroll
            for (int nt = 0; nt < 4; nt++) {
                int dl = wn * 64 + nt * 16 + l15;
                int tl = wm * 64 + mt * 16 + qd * 4;
                uint2 pk2;
                pk2.x = pkbf(acc[mt][nt][0], acc[mt][nt][1]);
                pk2.y = pkbf(acc[mt][nt][2], acc[mt][nt][3]);
                *(uint2*)(T + dl * 136 + tl) = pk2;
            }
        asm volatile("s_waitcnt lgkmcnt(0)" ::: "memory");
        BARF();
#pragma unroll
        for (int p = 0; p < 8; ++p) {
            int idx = p * (NW * 64) + tid;
            int dd = idx >> 4, u = idx & 15;
            uint4 vv = *(const uint4*)(T + dd * 136 + u * 8);
            *(uint4*)(O1 + (size_t)(bq * 1024 + n0 + dd) * 1024 + t0 + u * 8) = vv;
        }
    }
}

__global__ __launch_bounds__(512, 4) void k_qkvg(const unsigned short* __restrict__ xr16,
                                                 const unsigned short* __restrict__ xk16,
                                                 const unsigned short* __restrict__ xv16,
                                                 const unsigned short* __restrict__ xg16,
                                                 const unsigned short* __restrict__ Wrb,
                                                 const unsigned short* __restrict__ Wkb,
                                                 const unsigned short* __restrict__ Wvb,
                                                 const unsigned short* __restrict__ Wgb,
                                                 unsigned short* __restrict__ qf, unsigned short* __restrict__ qb,
                                                 unsigned short* __restrict__ kf, unsigned short* __restrict__ kb,
                                                 unsigned short* __restrict__ vvt,
                                                 float* __restrict__ gg,
                                                 const float* __restrict__ cf, const float* __restrict__ cb) {
    __shared__ __align__(16) char smem[73728];
    // bijective XCD swizzle (512 % 8 == 0): XCD x gets 64 contiguous work ids
    int flat = blockIdx.x;
    int wkid = (flat & 7) * 64 + (flat >> 3);
    int gy = wkid >> 7;                        // which GEMM (128 tiles each)
    int rem = wkid & 127;
    int m0 = (rem >> 2) * 128, n0 = (rem & 3) * 256;
    const unsigned short* Ap = (gy == 0) ? xr16 : (gy == 1) ? xk16 : (gy == 2) ? xv16 : xg16;
    const unsigned short* Wp = (gy == 0) ? Wrb : (gy == 1) ? Wkb : (gy == 2) ? Wvb : Wgb;
    int mode = (gy == 0) ? 2 : (gy == 1) ? 3 : (gy == 2) ? 4 : 1;
    unsigned short* o1 = (gy == 0) ? qf : (gy == 1) ? kf : (gy == 2) ? vvt : nullptr;
    unsigned short* o2 = (gy == 0) ? qb : (gy == 1) ? kb : nullptr;
    float* cfo = (gy == 3) ? gg : nullptr;
    gemm_v5<8, 256>(Ap, Wp, m0, n0, mode, cfo, o1, o2, cf, cb, smem);
}

__global__ __launch_bounds__(256, 3) void k_gemmo(const unsigned short* __restrict__ z16,
                                                  const unsigned short* __restrict__ Wob,
                                                  float* __restrict__ out) {
    __shared__ __align__(16) char smem[49152];
    int flat = blockIdx.x;                     // grid 256 (256 % 8 == 0)
    int wkid = (flat & 7) * 32 + (flat >> 3);
    int m0 = (wkid >> 3) * 128, n0 = (wkid & 7) * 128;
    gemm_v5<4, 128>(z16, Wob, m0, n0, 0, out, nullptr, nullptr, nullptr, nullptr, smem);
}

// ---------- attention v3: staged (4-wave shared tiles) + ring-2 counted vmcnt ----------
// r9 lesson: per-lane fragment gathers from global = 64 cache lines/instr and 4x
// duplicated L2 traffic (no cross-wave sharing) -> L2-transaction-bound (MfmaUtil 9.5%).
// Staging via GLD16 is the coalescing device; upgrade its schedule: double-buffer
// rounds (2 j-tiles each), issue next round's 8 loads before waiting, s_waitcnt
// vmcnt(8) (counted, not drain) + barrier. Trailing barrier protects buffer reuse.
__global__ __launch_bounds__(256, 2) void k_attn(const unsigned short* __restrict__ qf,
                                                 const unsigned short* __restrict__ qb,
                                                 const unsigned short* __restrict__ kf,
                                                 const unsigned short* __restrict__ kb,
                                                 const unsigned short* __restrict__ vvt,
                                                 float* __restrict__ y) {
    __shared__ __align__(16) char smem[65536];
    // round buffer rb: K tiles at rb*16384 + u*4096 (shorts), V at rb*16384 + 8192 + u*4096
    unsigned short* S = (unsigned short*)smem;
    int tid = threadIdx.x;
    int w = tid >> 6, lane = tid & 63, l15 = lane & 15, qd = lane >> 4;
    int bid = blockIdx.x;            // grid 512 = 64 bh x 8 itile, XCD-swizzled
    int bh = (bid & 7) + ((bid >> 6) << 3);
    int ib = (bid >> 3) & 7;
    int b = bh >> 4, h = bh & 15;
    int i0w = ib * 128 + w * 32;
    int bt0 = b * 1024;
    const unsigned short* vrow = vvt + (size_t)(b * 1024 + h * 64 + w * 16 + l15) * 1024 + qd * 8;
    int fmax = (i0w + 31) >> 6;
    int bmin = i0w >> 6;
    int srcA = l15 + ((lane & 16) << 1);
    int srcB = srcA + 16;
    fx4 yacc[4][2];
#pragma unroll
    for (int mt = 0; mt < 4; mt++)
#pragma unroll
        for (int nt = 0; nt < 2; nt++)
#pragma unroll
            for (int r = 0; r < 4; r++) yacc[mt][nt][r] = 0.f;

    for (int phase = 0; phase < 2; phase++) {
        const unsigned short* Q = phase ? qb : qf;
        const unsigned short* K = phase ? kb : kf;
        bh8 qfr[2][2];
#pragma unroll
        for (int nt = 0; nt < 2; nt++)
#pragma unroll
            for (int ks = 0; ks < 2; ks++)
                qfr[nt][ks] = *(const bh8*)(Q + (size_t)(bt0 + i0w + nt * 16 + l15) * 1024
                                              + h * 64 + ks * 32 + qd * 8);
        int jlo = phase == 0 ? 0 : 2 * ib;            // both ranges have EVEN length
        int nr  = phase == 0 ? (ib + 1) : (8 - ib);   // rounds of 2 j-tiles
        const unsigned short* krow = K + (size_t)(bt0 + w * 16 + l15) * 1024 + h * 64 + qd * 8;

#define ASTAGE(jt2v, rb) do { \
    _Pragma("unroll") \
    for (int u = 0; u < 2; ++u) { \
        size_t jbs = (size_t)((jt2v) + u) * 64; \
        unsigned short* kd = S + (rb) * 16384 + u * 4096 + w * 512; \
        unsigned short* vd = S + (rb) * 16384 + 8192 + u * 4096 + w * 512; \
        GLD16(krow + jbs * 1024,      kd); \
        GLD16(krow + jbs * 1024 + 32, kd + 2048); \
        GLD16(vrow + jbs,             vd); \
        GLD16(vrow + jbs + 32,        vd + 2048); \
    } \
} while (0)

        ASTAGE(jlo, 0);
        for (int ridx = 0; ridx < nr; ++ridx) {
            int jt2 = jlo + ridx * 2;
            if (ridx + 1 < nr) {
                ASTAGE(jt2 + 2, (ridx + 1) & 1);
                asm volatile("s_waitcnt vmcnt(8)" ::: "memory");   // this round resident
            } else {
                asm volatile("s_waitcnt vmcnt(0)" ::: "memory");
            }
            BARF();
            int rb = ridx & 1;
#pragma unroll
            for (int u = 0; u < 2; ++u) {
                int jt = jt2 + u;
                int jb = jt * 64;
                const unsigned short* bK = S + rb * 16384 + u * 4096;
                const unsigned short* bV = bK + 8192;
                bool active = (phase == 0) ? (jt <= fmax) : (jt >= bmin);
                if (!active) continue;
                bool needmask = (phase == 0) ? (jb + 63 > i0w) : (i0w + 31 >= jb);
                bh8 kc[8];
#pragma unroll
                for (int fi = 0; fi < 8; fi++)
                    kc[fi] = *(const bh8*)(bK + fi * 512 + lane * 8);
                fx4 sacc[4][2];
#pragma unroll
                for (int mt = 0; mt < 4; mt++)
#pragma unroll
                    for (int nt = 0; nt < 2; nt++)
#pragma unroll
                        for (int r = 0; r < 4; r++) sacc[mt][nt][r] = 0.f;
                __builtin_amdgcn_s_setprio(1);
#pragma unroll
                for (int ks = 0; ks < 2; ks++)
#pragma unroll
                    for (int mt = 0; mt < 4; mt++)
#pragma unroll
                        for (int nt = 0; nt < 2; nt++)
                            sacc[mt][nt] = __builtin_amdgcn_mfma_f32_16x16x32_bf16(kc[ks * 4 + mt], qfr[nt][ks], sacc[mt][nt], 0, 0, 0);
                __builtin_amdgcn_s_setprio(0);
                uint2 pk[4][2];
#pragma unroll
                for (int mt = 0; mt < 4; mt++)
#pragma unroll
                    for (int nt = 0; nt < 2; nt++) {
                        fx4 s = sacc[mt][nt];
                        if (needmask) {
                            int ii = i0w + nt * 16 + l15;
                            int jj0 = jb + mt * 16 + qd * 4;
#pragma unroll
                            for (int r = 0; r < 4; r++) {
                                bool keep = (phase == 0) ? (ii >= jj0 + r) : (ii < jj0 + r);
                                if (!keep) s[r] = 0.f;
                            }
                        }
                        pk[mt][nt].x = pkbf(s[0], s[1]);
                        pk[mt][nt].y = pkbf(s[2], s[3]);
                    }
                bh8 vc[8];
#pragma unroll
                for (int fi = 0; fi < 8; fi++)
                    vc[fi] = *(const bh8*)(bV + fi * 512 + lane * 8);
#pragma unroll
                for (int ks2 = 0; ks2 < 2; ks2++) {
#pragma unroll
                    for (int nt = 0; nt < 2; nt++) {
                        int lox  = __shfl((int)pk[2 * ks2][nt].x,     srcA);
                        int hix  = __shfl((int)pk[2 * ks2 + 1][nt].x, srcA);
                        int loy  = __shfl((int)pk[2 * ks2][nt].y,     srcA);
                        int hiy  = __shfl((int)pk[2 * ks2 + 1][nt].y, srcA);
                        int lox2 = __shfl((int)pk[2 * ks2][nt].x,     srcB);
                        int hix2 = __shfl((int)pk[2 * ks2 + 1][nt].x, srcB);
                        int loy2 = __shfl((int)pk[2 * ks2][nt].y,     srcB);
                        int hiy2 = __shfl((int)pk[2 * ks2 + 1][nt].y, srcB);
                        union { int4 i; bh8 h; } cv;
                        cv.i.x = (qd & 2) ? hix  : lox;
                        cv.i.y = (qd & 2) ? hiy  : loy;
                        cv.i.z = (qd & 2) ? hix2 : lox2;
                        cv.i.w = (qd & 2) ? hiy2 : loy2;
                        __builtin_amdgcn_s_setprio(1);
#pragma unroll
                        for (int mt = 0; mt < 4; mt++)
                            yacc[mt][nt] = __builtin_amdgcn_mfma_f32_16x16x32_bf16(vc[ks2 * 4 + mt], cv.h, yacc[mt][nt], 0, 0, 0);
                        __builtin_amdgcn_s_setprio(0);
                    }
                }
            }
            BARF();   // all waves done reading this buffer before it is restaged
        }
#undef ASTAGE
    }
    // store y^T C-frags: i = col, d = row -> float4 along d
#pragma unroll
    for (int mt = 0; mt < 4; mt++)
#pragma unroll
        for (int nt = 0; nt < 2; nt++) {
            fx4 s = yacc[mt][nt];
            float4 o; o.x = s[0]; o.y = s[1]; o.z = s[2]; o.w = s[3];
            *(float4*)&y[(size_t)(bt0 + i0w + nt * 16 + l15) * 1024 + h * 64 + mt * 16 + qd * 4] = o;
        }
}

// ---------- groupnorm * g -> bf16 z ----------
__global__ __launch_bounds__(256) void k_gn(const float* __restrict__ y,
                                            const float* __restrict__ g,
                                            const float* __restrict__ lnw,
                                            const float* __restrict__ lnb,
                                            unsigned short* __restrict__ z16) {
    int tid = threadIdx.x;
    int lane = tid & 63;
    int wv = tid >> 6;
    int group = blockIdx.x * 4 + wv;     // grid 16384
    int tok = group >> 4, h = group & 15;
    int d = h * 64 + lane;
    size_t idx = (size_t)tok * 1024 + d;
    float val = y[idx];
    float s = val, s2 = val * val;
#pragma unroll
    for (int off = 32; off > 0; off >>= 1) {
        s  += __shfl_xor(s, off, 64);
        s2 += __shfl_xor(s2, off, 64);
    }
    float mu = s * (1.f / 64.f);
    float var = s2 * (1.f / 64.f) - mu * mu;
    float inv = rsqrtf(var + 6.4e-4f);
    float yn = (val - mu) * inv * lnw[d] + lnb[d];
    z16[idx] = f2bf(yn * g[idx]);
}

extern "C" void kernel_launch(void* const* d_in, const int* in_sizes, int n_in,
                              void* d_out, int out_size, void* d_ws, size_t ws_size,
                              hipStream_t stream) {
    const float* x     = (const float*)d_in[0];
    const float* maa_x = (const float*)d_in[1];
    const float* maa_w = (const float*)d_in[2];
    const float* maa_k = (const float*)d_in[3];
    const float* maa_v = (const float*)d_in[4];
    const float* maa_r = (const float*)d_in[5];
    const float* maa_g = (const float*)d_in[6];
    const float* w1    = (const float*)d_in[7];
    const float* w2    = (const float*)d_in[8];
    const float* tdec  = (const float*)d_in[9];
    const float* dw1   = (const float*)d_in[10];
    const float* dw2   = (const float*)d_in[11];
    const float* W_r   = (const float*)d_in[12];
    const float* W_k   = (const float*)d_in[13];
    const float* W_v   = (const float*)d_in[14];
    const float* W_g   = (const float*)d_in[15];
    const float* W_o   = (const float*)d_in[16];
    const float* lnw   = (const float*)d_in[17];
    const float* lnb   = (const float*)d_in[18];

    float* ws = (float*)d_ws;
    size_t o = 0;
    float* dech   = ws + o; o += 262144;
    float* segsum = ws + o; o += 131072;
    float* ew     = ws + o; o += 4194304;
    float* cf     = ws + o; o += 4194304;
    float* cb     = ws + o; o += 4194304;
    float* gg     = ws + o; o += 4194304;
    unsigned short* us = (unsigned short*)(ws + o);
    size_t u = 0;
    unsigned short* xmix16 = us + u; u += 4194304;
    unsigned short* xw16 = us + u; u += 4194304;
    unsigned short* xr16 = us + u; u += 4194304;   // also z16 after gemm4
    unsigned short* xk16 = us + u; u += 4194304;
    unsigned short* xv16 = us + u; u += 4194304;
    unsigned short* xg16 = us + u; u += 4194304;
    unsigned short* qf   = us + u; u += 4194304;
    unsigned short* qb   = us + u; u += 4194304;
    unsigned short* kf   = us + u; u += 4194304;
    unsigned short* kb   = us + u; u += 4194304;
    unsigned short* vvt  = us + u; u += 4194304;
    unsigned short* Wrb  = us + u; u += 1048576;
    unsigned short* Wkb  = us + u; u += 1048576;
    unsigned short* Wvb  = us + u; u += 1048576;
    unsigned short* Wgb  = us + u; u += 1048576;
    unsigned short* Wob  = us + u; u += 1048576;
    unsigned short* w1T  = us + u; u += 163840;
    unsigned short* dw1T = us + u; u += 65536;
    unsigned short* xxx16 = us + u; u += 655360;
    unsigned short* w2T16 = us + u; u += 163840;
    float* yb0 = cf;               // attention output reuses cf (dead after gemm4)
    unsigned short* z16 = xr16;    // dead after gemm4

    k_prep<<<dim3(640, 7), 256, 0, stream>>>(W_r, W_k, W_v, W_g, W_o, w1, dw1, w2,
                                             Wrb, Wkb, Wvb, Wgb, Wob, w1T, dw1T, w2T16);
    k_mixx<<<4096, 256, 0, stream>>>(x, maa_x, xmix16);
    k_xxx2<<<256, 256, 0, stream>>>(xmix16, w1T, xxx16);
    k_mmix<<<dim3(16, 32), 256, 0, stream>>>(x, xxx16, w2T16, maa_w, maa_k, maa_v, maa_r, maa_g,
                                             xw16, xk16, xv16, xr16, xg16);
    k_dec1m<<<256, 256, 0, stream>>>(xw16, dw1T, dech);
    k_dec2<<<512, 256, 0, stream>>>(dech, dw2, tdec, ew);
    k_scan1<<<2048, 64, 0, stream>>>(ew, segsum);
    k_scan3<<<2048, 64, 0, stream>>>(ew, segsum, cf, cb);
    k_qkvg<<<dim3(512), dim3(512), 0, stream>>>(xr16, xk16, xv16, xg16, Wrb, Wkb, Wvb, Wgb,
                                                qf, qb, kf, kb, vvt, gg, cf, cb);
    k_attn<<<512, 256, 0, stream>>>(qf, qb, kf, kb, vvt, yb0);
    k_gn<<<16384, 256, 0, stream>>>(yb0, gg, lnw, lnb, z16);
    k_gemmo<<<256, 256, 0, stream>>>(z16, Wob, (float*)d_out);
}

// Round 11
// 324.510 us; speedup vs baseline: 1.0968x; 1.0063x over previous
//
#include <hip/hip_runtime.h>
#include <math.h>

#define NB 4
#define TT 1024
#define DD 1024
#define NTOK 4096
#define ND (NTOK*DD)

typedef __attribute__((ext_vector_type(8))) short bh8;
typedef __attribute__((ext_vector_type(4))) float fx4;

__device__ __forceinline__ unsigned short f2bf(float f) {
    unsigned int b = __float_as_uint(f);
    b += 0x7fffu + ((b >> 16) & 1u);
    return (unsigned short)(b >> 16);
}

// pack two fp32 -> packed bf16 (RNE); HW v_cvt_pk_bf16_f32 when available
__device__ __forceinline__ unsigned pkbf(float a, float b) {
#if __has_builtin(__builtin_amdgcn_cvt_pk_bf16_f32)
    auto r = __builtin_amdgcn_cvt_pk_bf16_f32(a, b);
    unsigned u;
    __builtin_memcpy(&u, &r, 4);
    return u;
#else
    return ((unsigned)f2bf(b) << 16) | f2bf(a);
#endif
}

// async global->LDS, 16B per lane, LDS dst = wave-uniform base + lane*16
#define GLD16(gp, lp) __builtin_amdgcn_global_load_lds( \
    (__attribute__((address_space(1))) void*)(gp), \
    (__attribute__((address_space(3))) void*)(lp), 16, 0, 0)

// barrier that is also a compiler memory fence
#define BARF() do { __builtin_amdgcn_s_barrier(); asm volatile("" ::: "memory"); } while (0)

// ---------- fused preprocessing: 5x wconv, w1T, dw1T, w2T ----------
__global__ __launch_bounds__(256) void k_prep(const float* __restrict__ W_r, const float* __restrict__ W_k,
                                              const float* __restrict__ W_v, const float* __restrict__ W_g,
                                              const float* __restrict__ W_o,
                                              const float* __restrict__ w1, const float* __restrict__ dw1,
                                              const float* __restrict__ w2,
                                              unsigned short* __restrict__ Wrb, unsigned short* __restrict__ Wkb,
                                              unsigned short* __restrict__ Wvb, unsigned short* __restrict__ Wgb,
                                              unsigned short* __restrict__ Wob,
                                              unsigned short* __restrict__ w1T, unsigned short* __restrict__ dw1T,
                                              unsigned short* __restrict__ w2T16) {
    int y = blockIdx.y, bx = blockIdx.x, tid = threadIdx.x;   // grid (640, 7)
    if (y < 5) {
        if (bx >= 512) return;
        const float* s = (y == 0) ? W_r : (y == 1) ? W_k : (y == 2) ? W_v : (y == 3) ? W_g : W_o;
        unsigned short* d = (y == 0) ? Wrb : (y == 1) ? Wkb : (y == 2) ? Wvb : (y == 3) ? Wgb : Wob;
        int i = (bx * 256 + tid) * 8;
        float4 a = *(const float4*)(s + i);
        float4 b = *(const float4*)(s + i + 4);
        uint4 o;
        o.x = pkbf(a.x, a.y);
        o.y = pkbf(a.z, a.w);
        o.z = pkbf(b.x, b.y);
        o.w = pkbf(b.z, b.w);
        *(uint4*)(d + i) = o;
    } else if (y == 5) {
        int o = bx * 256 + tid;          // 163840 total
        int r = o & 1023, c = o >> 10;
        w1T[o] = f2bf(w1[r * 160 + c]);
    } else {
        if (bx < 256) {
            int o = bx * 256 + tid;      // 65536 total
            int r = o & 1023, c = o >> 10;
            dw1T[o] = f2bf(dw1[r * 64 + c]);
        } else if (bx < 276) {
            int wi = bx - 256;
            int f = wi >> 2;
            int d = (wi & 3) * 256 + tid;
#pragma unroll 8
            for (int m = 0; m < 32; m++)
                w2T16[(size_t)(f * 1024 + d) * 32 + m] = f2bf(w2[(size_t)(f * 32 + m) * 1024 + d]);
        }
    }
}

// ---------- k1: xmix16 = bf16(x + dxprev * maa_x) ----------
__global__ __launch_bounds__(256) void k_mixx(const float* __restrict__ x,
                                              const float* __restrict__ maa_x,
                                              unsigned short* __restrict__ xmix16) {
    int base = (blockIdx.x * 256 + threadIdx.x) * 4;   // grid 4096
    int t = (base >> 10) & 1023;
    int d = base & 1023;
    float4 xv = *(const float4*)(x + base);
    float4 xm = (t > 0)    ? *(const float4*)(x + base - 1024) : make_float4(0, 0, 0, 0);
    float4 xp = (t < 1023) ? *(const float4*)(x + base + 1024) : make_float4(0, 0, 0, 0);
    float4 ma = *(const float4*)(maa_x + d);
    uint2 o;
    float a0 = xv.x + (0.5f * (xm.x + xp.x) - xv.x) * ma.x;
    float a1 = xv.y + (0.5f * (xm.y + xp.y) - xv.y) * ma.y;
    float a2 = xv.z + (0.5f * (xm.z + xp.z) - xv.z) * ma.z;
    float a3 = xv.w + (0.5f * (xm.w + xp.w) - xv.w) * ma.w;
    o.x = pkbf(a0, a1);
    o.y = pkbf(a2, a3);
    *(uint2*)(xmix16 + base) = o;
}

// ---------- k2: xxx16 = bf16(tanh(xmix @ w1)), 4-wave K-split ----------
__global__ __launch_bounds__(256) void k_xxx2(const unsigned short* __restrict__ xmix16,
                                              const unsigned short* __restrict__ w1T,
                                              unsigned short* __restrict__ xxx16) {
    __shared__ __align__(16) float red[4][10][64][4];   // 40 KB
    int tid = threadIdx.x;
    int lane = tid & 63, wv = tid >> 6;
    int l15 = lane & 15, qd = lane >> 4;
    int m0 = blockIdx.x * 16;    // grid 256
    fx4 acc[10];
#pragma unroll
    for (int nt = 0; nt < 10; nt++)
#pragma unroll
        for (int r = 0; r < 4; r++) acc[nt][r] = 0.f;
    int kb0 = wv * 256;
#pragma unroll 2
    for (int kb = kb0; kb < kb0 + 256; kb += 32) {
        bh8 af = *(const bh8*)(xmix16 + (size_t)(m0 + l15) * 1024 + kb + qd * 8);
#pragma unroll
        for (int nt = 0; nt < 10; nt++) {
            bh8 bf = *(const bh8*)(w1T + (size_t)(nt * 16 + l15) * 1024 + kb + qd * 8);
            acc[nt] = __builtin_amdgcn_mfma_f32_16x16x32_bf16(af, bf, acc[nt], 0, 0, 0);
        }
    }
#pragma unroll
    for (int nt = 0; nt < 10; nt++)
        *(fx4*)&red[wv][nt][lane][0] = acc[nt];
    __syncthreads();
    if (wv == 0) {
#pragma unroll
        for (int nt = 0; nt < 10; nt++) {
            fx4 s = *(const fx4*)&red[0][nt][lane][0];
            s = s + *(const fx4*)&red[1][nt][lane][0];
            s = s + *(const fx4*)&red[2][nt][lane][0];
            s = s + *(const fx4*)&red[3][nt][lane][0];
#pragma unroll
            for (int r = 0; r < 4; r++)
                xxx16[(size_t)(m0 + qd * 4 + r) * 160 + nt * 16 + l15] = f2bf(tanhf(s[r]));
        }
    }
}

// ---------- k3: fused mm-einsum (MFMA, K=32) + five mixes, no LDS ----------
__global__ __launch_bounds__(256, 2) void k_mmix(const float* __restrict__ x,
                                                 const unsigned short* __restrict__ xxx16,
                                                 const unsigned short* __restrict__ w2T16,
                                                 const float* __restrict__ maa_w,
                                                 const float* __restrict__ maa_k,
                                                 const float* __restrict__ maa_v,
                                                 const float* __restrict__ maa_r,
                                                 const float* __restrict__ maa_g,
                                                 unsigned short* __restrict__ xw16,
                                                 unsigned short* __restrict__ xk16,
                                                 unsigned short* __restrict__ xv16,
                                                 unsigned short* __restrict__ xr16,
                                                 unsigned short* __restrict__ xg16) {
    int tid = threadIdx.x;
    int w = tid >> 6, lane = tid & 63, l15 = lane & 15, qd = lane >> 4;
    int n0 = blockIdx.x * 64;               // grid (16, 32)
    int m0w = blockIdx.y * 128 + w * 32;
    const float* maap[5] = {maa_w, maa_k, maa_v, maa_r, maa_g};
    unsigned short* outp[5] = {xw16, xk16, xv16, xr16, xg16};
    float xin[8][4], dxv[8][4];
#pragma unroll
    for (int mi = 0; mi < 2; mi++)
#pragma unroll
        for (int r = 0; r < 4; r++) {
            int tok = m0w + mi * 16 + qd * 4 + r;
            int t = tok & 1023;
#pragma unroll
            for (int ni = 0; ni < 4; ni++) {
                int d = n0 + ni * 16 + l15;
                size_t idx = (size_t)tok * 1024 + d;
                float xv = x[idx];
                float xm1 = (t > 0)    ? x[idx - 1024] : 0.f;
                float xp1 = (t < 1023) ? x[idx + 1024] : 0.f;
                xin[mi * 4 + r][ni] = xv;
                dxv[mi * 4 + r][ni] = 0.5f * (xm1 + xp1) - xv;
            }
        }
#pragma unroll
    for (int f = 0; f < 5; f++) {
        bh8 af[2], bf[4];
#pragma unroll
        for (int mi = 0; mi < 2; mi++)
            af[mi] = *(const bh8*)(xxx16 + (size_t)(m0w + mi * 16 + l15) * 160 + f * 32 + qd * 8);
#pragma unroll
        for (int ni = 0; ni < 4; ni++)
            bf[ni] = *(const bh8*)(w2T16 + (size_t)(f * 1024 + n0 + ni * 16 + l15) * 32 + qd * 8);
        fx4 acc[2][4];
#pragma unroll
        for (int mi = 0; mi < 2; mi++)
#pragma unroll
            for (int ni = 0; ni < 4; ni++) {
#pragma unroll
                for (int r = 0; r < 4; r++) acc[mi][ni][r] = 0.f;
                acc[mi][ni] = __builtin_amdgcn_mfma_f32_16x16x32_bf16(af[mi], bf[ni], acc[mi][ni], 0, 0, 0);
            }
        const float* maa = maap[f];
        unsigned short* op = outp[f];
#pragma unroll
        for (int ni = 0; ni < 4; ni++) {
            float mv = maa[n0 + ni * 16 + l15];
#pragma unroll
            for (int mi = 0; mi < 2; mi++)
#pragma unroll
                for (int r = 0; r < 4; r++) {
                    float o = xin[mi * 4 + r][ni] + dxv[mi * 4 + r][ni] * (mv + acc[mi][ni][r]);
                    op[(size_t)(m0w + mi * 16 + qd * 4 + r) * 1024 + n0 + ni * 16 + l15] = f2bf(o);
                }
        }
    }
}

// ---------- decay GEMM1: dech = tanh(xw @ dw1), 4-wave K-split ----------
__global__ __launch_bounds__(256) void k_dec1m(const unsigned short* __restrict__ xw16,
                                               const unsigned short* __restrict__ dw1T,
                                               float* __restrict__ dech) {
    __shared__ __align__(16) float red[4][4][64][4];    // 16 KB
    int tid = threadIdx.x;
    int lane = tid & 63, wv = tid >> 6;
    int l15 = lane & 15, qd = lane >> 4;
    int m0 = blockIdx.x * 16;    // grid 256
    fx4 acc[4];
#pragma unroll
    for (int nt = 0; nt < 4; nt++)
#pragma unroll
        for (int r = 0; r < 4; r++) acc[nt][r] = 0.f;
    int kb0 = wv * 256;
#pragma unroll 2
    for (int kb = kb0; kb < kb0 + 256; kb += 32) {
        bh8 af = *(const bh8*)(xw16 + (size_t)(m0 + l15) * 1024 + kb + qd * 8);
#pragma unroll
        for (int nt = 0; nt < 4; nt++) {
            bh8 bf = *(const bh8*)(dw1T + (size_t)(nt * 16 + l15) * 1024 + kb + qd * 8);
            acc[nt] = __builtin_amdgcn_mfma_f32_16x16x32_bf16(af, bf, acc[nt], 0, 0, 0);
        }
    }
#pragma unroll
    for (int nt = 0; nt < 4; nt++)
        *(fx4*)&red[wv][nt][lane][0] = acc[nt];
    __syncthreads();
    if (wv == 0) {
#pragma unroll
        for (int nt = 0; nt < 4; nt++) {
            fx4 s = *(const fx4*)&red[0][nt][lane][0];
            s = s + *(const fx4*)&red[1][nt][lane][0];
            s = s + *(const fx4*)&red[2][nt][lane][0];
            s = s + *(const fx4*)&red[3][nt][lane][0];
#pragma unroll
            for (int r = 0; r < 4; r++)
                dech[(size_t)(m0 + qd * 4 + r) * 64 + nt * 16 + l15] = tanhf(s[r]);
        }
    }
}

// ---------- decay GEMM2: ew = -exp(time_decay + dech @ dw2) ----------
__global__ __launch_bounds__(256) void k_dec2(const float* __restrict__ dech,
                                              const float* __restrict__ dw2,
                                              const float* __restrict__ tdec,
                                              float* __restrict__ ew) {
    __shared__ float hl[8][64];
    int tid = threadIdx.x;
    int tok0 = blockIdx.x * 8;     // grid 512
    {
        int l = tid;        hl[l >> 6][l & 63] = dech[tok0 * 64 + l];
        l = tid + 256;      hl[l >> 6][l & 63] = dech[tok0 * 64 + l];
    }
    __syncthreads();
#pragma unroll 1
    for (int c = 0; c < 4; c++) {
        int d = c * 256 + tid;
        float acc[8] = {};
#pragma unroll 8
        for (int j = 0; j < 64; j++) {
            float wv = dw2[j * 1024 + d];
#pragma unroll
            for (int g = 0; g < 8; g++) acc[g] = fmaf(hl[g][j], wv, acc[g]);
        }
        float td = tdec[d];
#pragma unroll
        for (int g = 0; g < 8; g++) ew[(tok0 + g) * 1024 + d] = -expf(td + acc[g]);
    }
}

// ---------- scan stage 1: per-segment sums (seg = 32) ----------
__global__ __launch_bounds__(64) void k_scan1(const float* __restrict__ ew, float* __restrict__ segsum) {
    int bx = blockIdx.x;            // grid 2048 = 4b x 32seg x 16dch
    int b = bx >> 9, seg = (bx >> 4) & 31, dch = bx & 15;
    int d = dch * 64 + threadIdx.x;
    size_t base = ((size_t)(b * 1024 + seg * 32)) * 1024 + d;
    float s = 0.f;
#pragma unroll 8
    for (int t = 0; t < 32; t++) s += ew[base + (size_t)t * 1024];
    segsum[(b * 32 + seg) * 1024 + d] = s;
}

// ---------- scan stage 2+3 fused: local prefix of segsums + emit clipped cf/cb ----------
__global__ __launch_bounds__(64) void k_scan3(const float* __restrict__ ew, const float* __restrict__ segsum,
                                              float* __restrict__ cf, float* __restrict__ cb) {
    int bx = blockIdx.x;            // grid 2048
    int b = bx >> 9, seg = (bx >> 4) & 31, dch = bx & 15;
    int d = dch * 64 + threadIdx.x;
    float run = 0.f, pre = 0.f, off16 = 0.f;
#pragma unroll
    for (int s = 0; s < 32; s++) {
        float tv = segsum[(b * 32 + s) * 1024 + d];
        if (s == seg) pre = run;
        if (s == 16) off16 = run;
        run += tv;
    }
    float e512 = ew[((size_t)(b * 1024 + 512)) * 1024 + d];
    float sb = off16;           // cs[511]
    float sf = off16 + e512;    // cs[512]
    float cum = pre;
    size_t base = ((size_t)(b * 1024 + seg * 32)) * 1024 + d;
#pragma unroll 4
    for (int t = 0; t < 32; t++) {
        float prev = cum;
        cum += ew[base + (size_t)t * 1024];
        cf[base + (size_t)t * 1024] = fminf(fmaxf(cum - sf, -60.f), 60.f);
        cb[base + (size_t)t * 1024] = fminf(fmaxf(prev - sb, -60.f), 60.f);
    }
}

// ---------- GEMM engine v5: occupancy-first. BM=128, BN templated, BK=32 ----------
// Wide  (NW=8, BN=256): 512 thr, wave 64x64 (64 AGPR), regs forced <=128 by
//   __launch_bounds__(512,4); LDS ring-3 x 24KB = 72KB -> 2 blocks x 8 waves
//   = 16 waves/CU (4/SIMD). Per wave/tile: 16 MFMA, 8 b128, 3 GLD16 -> vmcnt(3).
// Narrow (NW=4, BN=128): 256 thr, ring-3 x 16KB = 48KB -> 3 blocks/CU (12 waves).
// Zero-conflict swizzle proven in r4: stage gblk = lb ^ ((lr>>1)&3),
// read col qd ^ ((l15>>1)&3). One barrier/tile, counted vmcnt (never 0 till tail).
// modes: 0 fp32 out, 1 silu fp32, 2 q-exp (O1=qf,O2=qb), 3 k-exp, 4 v-transpose (O1=vvt)
template<int NW, int BNv>
__device__ __forceinline__ void gemm_v5(const unsigned short* __restrict__ A,
                                        const unsigned short* __restrict__ W,
                                        int m0, int n0, int mode,
                                        float* __restrict__ Cf,
                                        unsigned short* __restrict__ O1,
                                        unsigned short* __restrict__ O2,
                                        const float* __restrict__ cfp,
                                        const float* __restrict__ cbp,
                                        char* smem) {
    constexpr int AR = 128 / NW;          // A rows staged per wave
    constexpr int AG = AR / 16;           // GLD16s for A per wave
    constexpr int BR = BNv / NW;          // B rows per wave
    constexpr int BG = BR / 16;
    constexpr int LPW = AG + BG;          // loads per wave per tile
    constexpr int SLOT = (128 + BNv) * 64;   // ring slot bytes
    constexpr int WNC = BNv / 64;

    int tid = threadIdx.x;
    int lane = tid & 63, w = tid >> 6;
    int l15 = lane & 15, qd = lane >> 4;
    int wm = w / WNC, wn = w % WNC;
    int lr = lane >> 2, lb = lane & 3;
    int gblk = lb ^ ((lr >> 1) & 3);      // pre-swizzled global 16B-block
    const unsigned short* aSrc = A + (size_t)(m0 + w * AR + lr) * 1024 + gblk * 8;
    const unsigned short* bSrc = W + (size_t)(n0 + w * BR + lr) * 1024 + gblk * 8;
    int rc = (qd ^ ((l15 >> 1) & 3)) * 8; // swizzled frag col (shorts)
    int arow = (wm * 64 + l15) * 32 + rc;
    int brow = (wn * 64 + l15) * 32 + rc;

    auto stage = [&](int off, int kbv) {
        unsigned short* _sa = (unsigned short*)(smem + off);
        unsigned short* _sb = _sa + 128 * 32;
#pragma unroll
        for (int i = 0; i < AG; ++i)
            GLD16(aSrc + kbv + (size_t)i * 16 * 1024, _sa + (w * AR + i * 16) * 32);
#pragma unroll
        for (int i = 0; i < BG; ++i)
            GLD16(bSrc + kbv + (size_t)i * 16 * 1024, _sb + (w * BR + i * 16) * 32);
    };

    fx4 acc[4][4];
#pragma unroll
    for (int mt = 0; mt < 4; mt++)
#pragma unroll
        for (int nt = 0; nt < 4; nt++)
#pragma unroll
            for (int r = 0; r < 4; r++) acc[mt][nt][r] = 0.f;

    // prologue: tiles 0, 1
    stage(0, 0);
    stage(SLOT, 32);
    if constexpr (LPW == 3) asm volatile("s_waitcnt vmcnt(3)" ::: "memory");
    else                    asm volatile("s_waitcnt vmcnt(4)" ::: "memory");
    BARF();

    int oc = 0, on = SLOT, o2 = 2 * SLOT;
#pragma unroll 1
    for (int t = 0; t < 32; ++t) {
        if (t < 30) stage(o2, (t + 2) * 32);
        const unsigned short* cA = (const unsigned short*)(smem + oc);
        const unsigned short* cB = cA + 128 * 32;
        bh8 a[4], b[4];
#pragma unroll
        for (int mt = 0; mt < 4; ++mt) a[mt] = *(const bh8*)(cA + arow + mt * 512);
#pragma unroll
        for (int nt = 0; nt < 4; ++nt) b[nt] = *(const bh8*)(cB + brow + nt * 512);
        __builtin_amdgcn_s_setprio(1);
#pragma unroll
        for (int nt = 0; nt < 4; ++nt)
#pragma unroll
            for (int mt = 0; mt < 4; ++mt)
                acc[mt][nt] = __builtin_amdgcn_mfma_f32_16x16x32_bf16(a[mt], b[nt], acc[mt][nt], 0, 0, 0);
        __builtin_amdgcn_s_setprio(0);
        asm volatile("s_waitcnt lgkmcnt(0)" ::: "memory");
        if (t < 30) {
            if constexpr (LPW == 3) asm volatile("s_waitcnt vmcnt(3)" ::: "memory");
            else                    asm volatile("s_waitcnt vmcnt(4)" ::: "memory");
        } else if (t == 30) {
            asm volatile("s_waitcnt vmcnt(0)" ::: "memory");
        }
        BARF();
        int tmp = oc; oc = on; on = o2; o2 = tmp;
    }

    // ----- epilogues: per wave 64x64 at (m0 + wm*64, n0 + wn*64) -----
    int mb = m0 + wm * 64, nb = n0 + wn * 64;
    if (mode <= 1) {
#pragma unroll
        for (int mt = 0; mt < 4; mt++)
#pragma unroll
            for (int nt = 0; nt < 4; nt++)
#pragma unroll
                for (int r = 0; r < 4; r++) {
                    float v = acc[mt][nt][r];
                    if (mode == 1) v = v / (1.f + __expf(-v));
                    Cf[(size_t)(mb + mt * 16 + qd * 4 + r) * 1024 + nb + nt * 16 + l15] = v;
                }
    } else if (mode <= 3) {
        float s1 = (mode == 2) ? 1.f : -1.f;
#pragma unroll
        for (int mt = 0; mt < 4; mt++)
#pragma unroll
            for (int nt = 0; nt < 4; nt++)
#pragma unroll
                for (int r = 0; r < 4; r++) {
                    size_t idx = (size_t)(mb + mt * 16 + qd * 4 + r) * 1024 + nb + nt * 16 + l15;
                    float v = acc[mt][nt][r];
                    O1[idx] = f2bf(v * __expf(s1 * cfp[idx]));
                    O2[idx] = f2bf(v * __expf(-s1 * cbp[idx]));
                }
    } else {
        // V transpose: vvt[(b*1024 + d)][t]; T[BNv d][136] shorts
        unsigned short* T = (unsigned short*)smem;
        int bq = m0 >> 10, t0 = m0 & 1023;
#pragma unroll
        for (int mt = 0; mt < 4; mt++)
#pragma unroll
            for (int nt = 0; nt < 4; nt++) {
                int dl = wn * 64 + nt * 16 + l15;
                int tl = wm * 64 + mt * 16 + qd * 4;
                uint2 pk2;
                pk2.x = pkbf(acc[mt][nt][0], acc[mt][nt][1]);
                pk2.y = pkbf(acc[mt][nt][2], acc[mt][nt][3]);
                *(uint2*)(T + dl * 136 + tl) = pk2;
            }
        asm volatile("s_waitcnt lgkmcnt(0)" ::: "memory");
        BARF();
#pragma unroll
        for (int p = 0; p < 8; ++p) {
            int idx = p * (NW * 64) + tid;
            int dd = idx >> 4, u = idx & 15;
            uint4 vv = *(const uint4*)(T + dd * 136 + u * 8);
            *(uint4*)(O1 + (size_t)(bq * 1024 + n0 + dd) * 1024 + t0 + u * 8) = vv;
        }
    }
}

__global__ __launch_bounds__(512, 4) void k_qkvg(const unsigned short* __restrict__ xr16,
                                                 const unsigned short* __restrict__ xk16,
                                                 const unsigned short* __restrict__ xv16,
                                                 const unsigned short* __restrict__ xg16,
                                                 const unsigned short* __restrict__ Wrb,
                                                 const unsigned short* __restrict__ Wkb,
                                                 const unsigned short* __restrict__ Wvb,
                                                 const unsigned short* __restrict__ Wgb,
                                                 unsigned short* __restrict__ qf, unsigned short* __restrict__ qb,
                                                 unsigned short* __restrict__ kf, unsigned short* __restrict__ kb,
                                                 unsigned short* __restrict__ vvt,
                                                 float* __restrict__ gg,
                                                 const float* __restrict__ cf, const float* __restrict__ cb) {
    __shared__ __align__(16) char smem[73728];
    // bijective XCD swizzle (512 % 8 == 0): XCD x gets 64 contiguous work ids
    int flat = blockIdx.x;
    int wkid = (flat & 7) * 64 + (flat >> 3);
    int gy = wkid >> 7;                        // which GEMM (128 tiles each)
    int rem = wkid & 127;
    int m0 = (rem >> 2) * 128, n0 = (rem & 3) * 256;
    const unsigned short* Ap = (gy == 0) ? xr16 : (gy == 1) ? xk16 : (gy == 2) ? xv16 : xg16;
    const unsigned short* Wp = (gy == 0) ? Wrb : (gy == 1) ? Wkb : (gy == 2) ? Wvb : Wgb;
    int mode = (gy == 0) ? 2 : (gy == 1) ? 3 : (gy == 2) ? 4 : 1;
    unsigned short* o1 = (gy == 0) ? qf : (gy == 1) ? kf : (gy == 2) ? vvt : nullptr;
    unsigned short* o2 = (gy == 0) ? qb : (gy == 1) ? kb : nullptr;
    float* cfo = (gy == 3) ? gg : nullptr;
    gemm_v5<8, 256>(Ap, Wp, m0, n0, mode, cfo, o1, o2, cf, cb, smem);
}

__global__ __launch_bounds__(256, 3) void k_gemmo(const unsigned short* __restrict__ z16,
                                                  const unsigned short* __restrict__ Wob,
                                                  float* __restrict__ out) {
    __shared__ __align__(16) char smem[49152];
    int flat = blockIdx.x;                     // grid 256 (256 % 8 == 0)
    int wkid = (flat & 7) * 32 + (flat >> 3);
    int m0 = (wkid >> 3) * 128, n0 = (wkid & 7) * 128;
    gemm_v5<4, 128>(z16, Wob, m0, n0, 0, out, nullptr, nullptr, nullptr, nullptr, smem);
}

// ---------- attention v4: ring-2 staged + fused GroupNorm*g epilogue -> z16 ----------
// The wave holds each token's full 64-d head group in yacc (qd lanes partition d):
// GN reduce = 16 in-lane adds + shfl_xor(16,32). Kills k_gn (one launch + 33.6MB
// y round-trip); attn stores 8B/lane bf16 z16 instead of 16B fp32 y.
__global__ __launch_bounds__(256, 2) void k_attn(const unsigned short* __restrict__ qf,
                                                 const unsigned short* __restrict__ qb,
                                                 const unsigned short* __restrict__ kf,
                                                 const unsigned short* __restrict__ kb,
                                                 const unsigned short* __restrict__ vvt,
                                                 const float* __restrict__ gg,
                                                 const float* __restrict__ lnw,
                                                 const float* __restrict__ lnb,
                                                 unsigned short* __restrict__ z16) {
    __shared__ __align__(16) char smem[65536];
    unsigned short* S = (unsigned short*)smem;
    int tid = threadIdx.x;
    int w = tid >> 6, lane = tid & 63, l15 = lane & 15, qd = lane >> 4;
    int bid = blockIdx.x;            // grid 512 = 64 bh x 8 itile, XCD-swizzled
    int bh = (bid & 7) + ((bid >> 6) << 3);
    int ib = (bid >> 3) & 7;
    int b = bh >> 4, h = bh & 15;
    int i0w = ib * 128 + w * 32;
    int bt0 = b * 1024;
    const unsigned short* vrow = vvt + (size_t)(b * 1024 + h * 64 + w * 16 + l15) * 1024 + qd * 8;
    int fmax = (i0w + 31) >> 6;
    int bmin = i0w >> 6;
    int srcA = l15 + ((lane & 16) << 1);
    int srcB = srcA + 16;
    fx4 yacc[4][2];
#pragma unroll
    for (int mt = 0; mt < 4; mt++)
#pragma unroll
        for (int nt = 0; nt < 2; nt++)
#pragma unroll
            for (int r = 0; r < 4; r++) yacc[mt][nt][r] = 0.f;

    for (int phase = 0; phase < 2; phase++) {
        const unsigned short* Q = phase ? qb : qf;
        const unsigned short* K = phase ? kb : kf;
        bh8 qfr[2][2];
#pragma unroll
        for (int nt = 0; nt < 2; nt++)
#pragma unroll
            for (int ks = 0; ks < 2; ks++)
                qfr[nt][ks] = *(const bh8*)(Q + (size_t)(bt0 + i0w + nt * 16 + l15) * 1024
                                              + h * 64 + ks * 32 + qd * 8);
        int jlo = phase == 0 ? 0 : 2 * ib;            // both ranges have EVEN length
        int nr  = phase == 0 ? (ib + 1) : (8 - ib);   // rounds of 2 j-tiles
        const unsigned short* krow = K + (size_t)(bt0 + w * 16 + l15) * 1024 + h * 64 + qd * 8;

#define ASTAGE(jt2v, rb) do { \
    _Pragma("unroll") \
    for (int u = 0; u < 2; ++u) { \
        size_t jbs = (size_t)((jt2v) + u) * 64; \
        unsigned short* kd = S + (rb) * 16384 + u * 4096 + w * 512; \
        unsigned short* vd = S + (rb) * 16384 + 8192 + u * 4096 + w * 512; \
        GLD16(krow + jbs * 1024,      kd); \
        GLD16(krow + jbs * 1024 + 32, kd + 2048); \
        GLD16(vrow + jbs,             vd); \
        GLD16(vrow + jbs + 32,        vd + 2048); \
    } \
} while (0)

        ASTAGE(jlo, 0);
        for (int ridx = 0; ridx < nr; ++ridx) {
            int jt2 = jlo + ridx * 2;
            if (ridx + 1 < nr) {
                ASTAGE(jt2 + 2, (ridx + 1) & 1);
                asm volatile("s_waitcnt vmcnt(8)" ::: "memory");   // this round resident
            } else {
                asm volatile("s_waitcnt vmcnt(0)" ::: "memory");
            }
            BARF();
            int rb = ridx & 1;
#pragma unroll
            for (int u = 0; u < 2; ++u) {
                int jt = jt2 + u;
                int jb = jt * 64;
                const unsigned short* bK = S + rb * 16384 + u * 4096;
                const unsigned short* bV = bK + 8192;
                bool active = (phase == 0) ? (jt <= fmax) : (jt >= bmin);
                if (!active) continue;
                bool needmask = (phase == 0) ? (jb + 63 > i0w) : (i0w + 31 >= jb);
                bh8 kc[8];
#pragma unroll
                for (int fi = 0; fi < 8; fi++)
                    kc[fi] = *(const bh8*)(bK + fi * 512 + lane * 8);
                fx4 sacc[4][2];
#pragma unroll
                for (int mt = 0; mt < 4; mt++)
#pragma unroll
                    for (int nt = 0; nt < 2; nt++)
#pragma unroll
                        for (int r = 0; r < 4; r++) sacc[mt][nt][r] = 0.f;
                __builtin_amdgcn_s_setprio(1);
#pragma unroll
                for (int ks = 0; ks < 2; ks++)
#pragma unroll
                    for (int mt = 0; mt < 4; mt++)
#pragma unroll
                        for (int nt = 0; nt < 2; nt++)
                            sacc[mt][nt] = __builtin_amdgcn_mfma_f32_16x16x32_bf16(kc[ks * 4 + mt], qfr[nt][ks], sacc[mt][nt], 0, 0, 0);
                __builtin_amdgcn_s_setprio(0);
                uint2 pk[4][2];
#pragma unroll
                for (int mt = 0; mt < 4; mt++)
#pragma unroll
                    for (int nt = 0; nt < 2; nt++) {
                        fx4 s = sacc[mt][nt];
                        if (needmask) {
                            int ii = i0w + nt * 16 + l15;
                            int jj0 = jb + mt * 16 + qd * 4;
#pragma unroll
                            for (int r = 0; r < 4; r++) {
                                bool keep = (phase == 0) ? (ii >= jj0 + r) : (ii < jj0 + r);
                                if (!keep) s[r] = 0.f;
                            }
                        }
                        pk[mt][nt].x = pkbf(s[0], s[1]);
                        pk[mt][nt].y = pkbf(s[2], s[3]);
                    }
                bh8 vc[8];
#pragma unroll
                for (int fi = 0; fi < 8; fi++)
                    vc[fi] = *(const bh8*)(bV + fi * 512 + lane * 8);
#pragma unroll
                for (int ks2 = 0; ks2 < 2; ks2++) {
#pragma unroll
                    for (int nt = 0; nt < 2; nt++) {
                        int lox  = __shfl((int)pk[2 * ks2][nt].x,     srcA);
                        int hix  = __shfl((int)pk[2 * ks2 + 1][nt].x, srcA);
                        int loy  = __shfl((int)pk[2 * ks2][nt].y,     srcA);
                        int hiy  = __shfl((int)pk[2 * ks2 + 1][nt].y, srcA);
                        int lox2 = __shfl((int)pk[2 * ks2][nt].x,     srcB);
                        int hix2 = __shfl((int)pk[2 * ks2 + 1][nt].x, srcB);
                        int loy2 = __shfl((int)pk[2 * ks2][nt].y,     srcB);
                        int hiy2 = __shfl((int)pk[2 * ks2 + 1][nt].y, srcB);
                        union { int4 i; bh8 h; } cv;
                        cv.i.x = (qd & 2) ? hix  : lox;
                        cv.i.y = (qd & 2) ? hiy  : loy;
                        cv.i.z = (qd & 2) ? hix2 : lox2;
                        cv.i.w = (qd & 2) ? hiy2 : loy2;
                        __builtin_amdgcn_s_setprio(1);
#pragma unroll
                        for (int mt = 0; mt < 4; mt++)
                            yacc[mt][nt] = __builtin_amdgcn_mfma_f32_16x16x32_bf16(vc[ks2 * 4 + mt], cv.h, yacc[mt][nt], 0, 0, 0);
                        __builtin_amdgcn_s_setprio(0);
                    }
                }
            }
            BARF();   // all waves done reading this buffer before it is restaged
        }
#undef ASTAGE
    }
    // ----- fused GroupNorm * g epilogue -> z16 -----
    // token = bt0 + i0w + nt*16 + l15; group d_local = mt*16 + qd*4 + r spans 0..63
    // across the 4 qd lanes with equal l15 -> reduce in-lane then shfl_xor 16,32.
#pragma unroll
    for (int nt = 0; nt < 2; nt++) {
        float s = 0.f, s2 = 0.f;
#pragma unroll
        for (int mt = 0; mt < 4; mt++)
#pragma unroll
            for (int r = 0; r < 4; r++) {
                float v = yacc[mt][nt][r];
                s += v;
                s2 += v * v;
            }
        s  += __shfl_xor(s, 16, 64);
        s2 += __shfl_xor(s2, 16, 64);
        s  += __shfl_xor(s, 32, 64);
        s2 += __shfl_xor(s2, 32, 64);
        float mu = s * (1.f / 64.f);
        float var = s2 * (1.f / 64.f) - mu * mu;
        float inv = rsqrtf(var + 6.4e-4f);
        size_t tokbase = (size_t)(bt0 + i0w + nt * 16 + l15) * 1024 + h * 64;
#pragma unroll
        for (int mt = 0; mt < 4; mt++) {
            int dl = mt * 16 + qd * 4;
            float4 lw = *(const float4*)(lnw + h * 64 + dl);
            float4 lb = *(const float4*)(lnb + h * 64 + dl);
            float4 gv = *(const float4*)(gg + tokbase + dl);
            float z0 = ((yacc[mt][nt][0] - mu) * inv * lw.x + lb.x) * gv.x;
            float z1 = ((yacc[mt][nt][1] - mu) * inv * lw.y + lb.y) * gv.y;
            float z2 = ((yacc[mt][nt][2] - mu) * inv * lw.z + lb.z) * gv.z;
            float z3 = ((yacc[mt][nt][3] - mu) * inv * lw.w + lb.w) * gv.w;
            uint2 o;
            o.x = pkbf(z0, z1);
            o.y = pkbf(z2, z3);
            *(uint2*)(z16 + tokbase + dl) = o;
        }
    }
}

extern "C" void kernel_launch(void* const* d_in, const int* in_sizes, int n_in,
                              void* d_out, int out_size, void* d_ws, size_t ws_size,
                              hipStream_t stream) {
    const float* x     = (const float*)d_in[0];
    const float* maa_x = (const float*)d_in[1];
    const float* maa_w = (const float*)d_in[2];
    const float* maa_k = (const float*)d_in[3];
    const float* maa_v = (const float*)d_in[4];
    const float* maa_r = (const float*)d_in[5];
    const float* maa_g = (const float*)d_in[6];
    const float* w1    = (const float*)d_in[7];
    const float* w2    = (const float*)d_in[8];
    const float* tdec  = (const float*)d_in[9];
    const float* dw1   = (const float*)d_in[10];
    const float* dw2   = (const float*)d_in[11];
    const float* W_r   = (const float*)d_in[12];
    const float* W_k   = (const float*)d_in[13];
    const float* W_v   = (const float*)d_in[14];
    const float* W_g   = (const float*)d_in[15];
    const float* W_o   = (const float*)d_in[16];
    const float* lnw   = (const float*)d_in[17];
    const float* lnb   = (const float*)d_in[18];

    float* ws = (float*)d_ws;
    size_t o = 0;
    float* dech   = ws + o; o += 262144;
    float* segsum = ws + o; o += 131072;
    float* ew     = ws + o; o += 4194304;
    float* cf     = ws + o; o += 4194304;
    float* cb     = ws + o; o += 4194304;
    float* gg     = ws + o; o += 4194304;
    unsigned short* us = (unsigned short*)(ws + o);
    size_t u = 0;
    unsigned short* xmix16 = us + u; u += 4194304;
    unsigned short* xw16 = us + u; u += 4194304;
    unsigned short* xr16 = us + u; u += 4194304;   // also z16 after gemm4
    unsigned short* xk16 = us + u; u += 4194304;
    unsigned short* xv16 = us + u; u += 4194304;
    unsigned short* xg16 = us + u; u += 4194304;
    unsigned short* qf   = us + u; u += 4194304;
    unsigned short* qb   = us + u; u += 4194304;
    unsigned short* kf   = us + u; u += 4194304;
    unsigned short* kb   = us + u; u += 4194304;
    unsigned short* vvt  = us + u; u += 4194304;
    unsigned short* Wrb  = us + u; u += 1048576;
    unsigned short* Wkb  = us + u; u += 1048576;
    unsigned short* Wvb  = us + u; u += 1048576;
    unsigned short* Wgb  = us + u; u += 1048576;
    unsigned short* Wob  = us + u; u += 1048576;
    unsigned short* w1T  = us + u; u += 163840;
    unsigned short* dw1T = us + u; u += 65536;
    unsigned short* xxx16 = us + u; u += 655360;
    unsigned short* w2T16 = us + u; u += 163840;
    unsigned short* z16 = xr16;    // dead after gemm4; attn writes gn output here

    k_prep<<<dim3(640, 7), 256, 0, stream>>>(W_r, W_k, W_v, W_g, W_o, w1, dw1, w2,
                                             Wrb, Wkb, Wvb, Wgb, Wob, w1T, dw1T, w2T16);
    k_mixx<<<4096, 256, 0, stream>>>(x, maa_x, xmix16);
    k_xxx2<<<256, 256, 0, stream>>>(xmix16, w1T, xxx16);
    k_mmix<<<dim3(16, 32), 256, 0, stream>>>(x, xxx16, w2T16, maa_w, maa_k, maa_v, maa_r, maa_g,
                                             xw16, xk16, xv16, xr16, xg16);
    k_dec1m<<<256, 256, 0, stream>>>(xw16, dw1T, dech);
    k_dec2<<<512, 256, 0, stream>>>(dech, dw2, tdec, ew);
    k_scan1<<<2048, 64, 0, stream>>>(ew, segsum);
    k_scan3<<<2048, 64, 0, stream>>>(ew, segsum, cf, cb);
    k_qkvg<<<dim3(512), dim3(512), 0, stream>>>(xr16, xk16, xv16, xg16, Wrb, Wkb, Wvb, Wgb,
                                                qf, qb, kf, kb, vvt, gg, cf, cb);
    k_attn<<<512, 256, 0, stream>>>(qf, qb, kf, kb, vvt, gg, lnw, lnb, z16);
    k_gemmo<<<256, 256, 0, stream>>>(z16, Wob, (float*)d_out);
}

// Round 12
// 316.096 us; speedup vs baseline: 1.1260x; 1.0266x over previous
//
#include <hip/hip_runtime.h>
#include <math.h>

#define NB 4
#define TT 1024
#define DD 1024
#define NTOK 4096
#define ND (NTOK*DD)

typedef __attribute__((ext_vector_type(8))) short bh8;
typedef __attribute__((ext_vector_type(4))) float fx4;

__device__ __forceinline__ unsigned short f2bf(float f) {
    unsigned int b = __float_as_uint(f);
    b += 0x7fffu + ((b >> 16) & 1u);
    return (unsigned short)(b >> 16);
}

// pack two fp32 -> packed bf16 (RNE); HW v_cvt_pk_bf16_f32 when available
__device__ __forceinline__ unsigned pkbf(float a, float b) {
#if __has_builtin(__builtin_amdgcn_cvt_pk_bf16_f32)
    auto r = __builtin_amdgcn_cvt_pk_bf16_f32(a, b);
    unsigned u;
    __builtin_memcpy(&u, &r, 4);
    return u;
#else
    return ((unsigned)f2bf(b) << 16) | f2bf(a);
#endif
}

// async global->LDS, 16B per lane, LDS dst = wave-uniform base + lane*16
#define GLD16(gp, lp) __builtin_amdgcn_global_load_lds( \
    (__attribute__((address_space(1))) void*)(gp), \
    (__attribute__((address_space(3))) void*)(lp), 16, 0, 0)

// barrier that is also a compiler memory fence
#define BARF() do { __builtin_amdgcn_s_barrier(); asm volatile("" ::: "memory"); } while (0)

// ---------- fused preprocessing: 5x wconv, w1T, dw1T, w2T ----------
__global__ __launch_bounds__(256) void k_prep(const float* __restrict__ W_r, const float* __restrict__ W_k,
                                              const float* __restrict__ W_v, const float* __restrict__ W_g,
                                              const float* __restrict__ W_o,
                                              const float* __restrict__ w1, const float* __restrict__ dw1,
                                              const float* __restrict__ w2,
                                              unsigned short* __restrict__ Wrb, unsigned short* __restrict__ Wkb,
                                              unsigned short* __restrict__ Wvb, unsigned short* __restrict__ Wgb,
                                              unsigned short* __restrict__ Wob,
                                              unsigned short* __restrict__ w1T, unsigned short* __restrict__ dw1T,
                                              unsigned short* __restrict__ w2T16) {
    int y = blockIdx.y, bx = blockIdx.x, tid = threadIdx.x;   // grid (640, 7)
    if (y < 5) {
        if (bx >= 512) return;
        const float* s = (y == 0) ? W_r : (y == 1) ? W_k : (y == 2) ? W_v : (y == 3) ? W_g : W_o;
        unsigned short* d = (y == 0) ? Wrb : (y == 1) ? Wkb : (y == 2) ? Wvb : (y == 3) ? Wgb : Wob;
        int i = (bx * 256 + tid) * 8;
        float4 a = *(const float4*)(s + i);
        float4 b = *(const float4*)(s + i + 4);
        uint4 o;
        o.x = pkbf(a.x, a.y);
        o.y = pkbf(a.z, a.w);
        o.z = pkbf(b.x, b.y);
        o.w = pkbf(b.z, b.w);
        *(uint4*)(d + i) = o;
    } else if (y == 5) {
        int o = bx * 256 + tid;          // 163840 total
        int r = o & 1023, c = o >> 10;
        w1T[o] = f2bf(w1[r * 160 + c]);
    } else {
        if (bx < 256) {
            int o = bx * 256 + tid;      // 65536 total
            int r = o & 1023, c = o >> 10;
            dw1T[o] = f2bf(dw1[r * 64 + c]);
        } else if (bx < 276) {
            int wi = bx - 256;
            int f = wi >> 2;
            int d = (wi & 3) * 256 + tid;
#pragma unroll 8
            for (int m = 0; m < 32; m++)
                w2T16[(size_t)(f * 1024 + d) * 32 + m] = f2bf(w2[(size_t)(f * 32 + m) * 1024 + d]);
        }
    }
}

// ---------- k1: xmix16 = bf16(x + dxprev * maa_x) ----------
__global__ __launch_bounds__(256) void k_mixx(const float* __restrict__ x,
                                              const float* __restrict__ maa_x,
                                              unsigned short* __restrict__ xmix16) {
    int base = (blockIdx.x * 256 + threadIdx.x) * 4;   // grid 4096
    int t = (base >> 10) & 1023;
    int d = base & 1023;
    float4 xv = *(const float4*)(x + base);
    float4 xm = (t > 0)    ? *(const float4*)(x + base - 1024) : make_float4(0, 0, 0, 0);
    float4 xp = (t < 1023) ? *(const float4*)(x + base + 1024) : make_float4(0, 0, 0, 0);
    float4 ma = *(const float4*)(maa_x + d);
    uint2 o;
    float a0 = xv.x + (0.5f * (xm.x + xp.x) - xv.x) * ma.x;
    float a1 = xv.y + (0.5f * (xm.y + xp.y) - xv.y) * ma.y;
    float a2 = xv.z + (0.5f * (xm.z + xp.z) - xv.z) * ma.z;
    float a3 = xv.w + (0.5f * (xm.w + xp.w) - xv.w) * ma.w;
    o.x = pkbf(a0, a1);
    o.y = pkbf(a2, a3);
    *(uint2*)(xmix16 + base) = o;
}

// ---------- k2: xxx16 = bf16(tanh(xmix @ w1)), 4-wave K-split ----------
__global__ __launch_bounds__(256) void k_xxx2(const unsigned short* __restrict__ xmix16,
                                              const unsigned short* __restrict__ w1T,
                                              unsigned short* __restrict__ xxx16) {
    __shared__ __align__(16) float red[4][10][64][4];   // 40 KB
    int tid = threadIdx.x;
    int lane = tid & 63, wv = tid >> 6;
    int l15 = lane & 15, qd = lane >> 4;
    int m0 = blockIdx.x * 16;    // grid 256
    fx4 acc[10];
#pragma unroll
    for (int nt = 0; nt < 10; nt++)
#pragma unroll
        for (int r = 0; r < 4; r++) acc[nt][r] = 0.f;
    int kb0 = wv * 256;
#pragma unroll 2
    for (int kb = kb0; kb < kb0 + 256; kb += 32) {
        bh8 af = *(const bh8*)(xmix16 + (size_t)(m0 + l15) * 1024 + kb + qd * 8);
#pragma unroll
        for (int nt = 0; nt < 10; nt++) {
            bh8 bf = *(const bh8*)(w1T + (size_t)(nt * 16 + l15) * 1024 + kb + qd * 8);
            acc[nt] = __builtin_amdgcn_mfma_f32_16x16x32_bf16(af, bf, acc[nt], 0, 0, 0);
        }
    }
#pragma unroll
    for (int nt = 0; nt < 10; nt++)
        *(fx4*)&red[wv][nt][lane][0] = acc[nt];
    __syncthreads();
    if (wv == 0) {
#pragma unroll
        for (int nt = 0; nt < 10; nt++) {
            fx4 s = *(const fx4*)&red[0][nt][lane][0];
            s = s + *(const fx4*)&red[1][nt][lane][0];
            s = s + *(const fx4*)&red[2][nt][lane][0];
            s = s + *(const fx4*)&red[3][nt][lane][0];
#pragma unroll
            for (int r = 0; r < 4; r++)
                xxx16[(size_t)(m0 + qd * 4 + r) * 160 + nt * 16 + l15] = f2bf(tanhf(s[r]));
        }
    }
}

// ---------- k3: fused mm-einsum (MFMA, K=32) + five mixes, no LDS ----------
__global__ __launch_bounds__(256, 2) void k_mmix(const float* __restrict__ x,
                                                 const unsigned short* __restrict__ xxx16,
                                                 const unsigned short* __restrict__ w2T16,
                                                 const float* __restrict__ maa_w,
                                                 const float* __restrict__ maa_k,
                                                 const float* __restrict__ maa_v,
                                                 const float* __restrict__ maa_r,
                                                 const float* __restrict__ maa_g,
                                                 unsigned short* __restrict__ xw16,
                                                 unsigned short* __restrict__ xk16,
                                                 unsigned short* __restrict__ xv16,
                                                 unsigned short* __restrict__ xr16,
                                                 unsigned short* __restrict__ xg16) {
    int tid = threadIdx.x;
    int w = tid >> 6, lane = tid & 63, l15 = lane & 15, qd = lane >> 4;
    int n0 = blockIdx.x * 64;               // grid (16, 32)
    int m0w = blockIdx.y * 128 + w * 32;
    const float* maap[5] = {maa_w, maa_k, maa_v, maa_r, maa_g};
    unsigned short* outp[5] = {xw16, xk16, xv16, xr16, xg16};
    float xin[8][4], dxv[8][4];
#pragma unroll
    for (int mi = 0; mi < 2; mi++)
#pragma unroll
        for (int r = 0; r < 4; r++) {
            int tok = m0w + mi * 16 + qd * 4 + r;
            int t = tok & 1023;
#pragma unroll
            for (int ni = 0; ni < 4; ni++) {
                int d = n0 + ni * 16 + l15;
                size_t idx = (size_t)tok * 1024 + d;
                float xv = x[idx];
                float xm1 = (t > 0)    ? x[idx - 1024] : 0.f;
                float xp1 = (t < 1023) ? x[idx + 1024] : 0.f;
                xin[mi * 4 + r][ni] = xv;
                dxv[mi * 4 + r][ni] = 0.5f * (xm1 + xp1) - xv;
            }
        }
#pragma unroll
    for (int f = 0; f < 5; f++) {
        bh8 af[2], bf[4];
#pragma unroll
        for (int mi = 0; mi < 2; mi++)
            af[mi] = *(const bh8*)(xxx16 + (size_t)(m0w + mi * 16 + l15) * 160 + f * 32 + qd * 8);
#pragma unroll
        for (int ni = 0; ni < 4; ni++)
            bf[ni] = *(const bh8*)(w2T16 + (size_t)(f * 1024 + n0 + ni * 16 + l15) * 32 + qd * 8);
        fx4 acc[2][4];
#pragma unroll
        for (int mi = 0; mi < 2; mi++)
#pragma unroll
            for (int ni = 0; ni < 4; ni++) {
#pragma unroll
                for (int r = 0; r < 4; r++) acc[mi][ni][r] = 0.f;
                acc[mi][ni] = __builtin_amdgcn_mfma_f32_16x16x32_bf16(af[mi], bf[ni], acc[mi][ni], 0, 0, 0);
            }
        const float* maa = maap[f];
        unsigned short* op = outp[f];
#pragma unroll
        for (int ni = 0; ni < 4; ni++) {
            float mv = maa[n0 + ni * 16 + l15];
#pragma unroll
            for (int mi = 0; mi < 2; mi++)
#pragma unroll
                for (int r = 0; r < 4; r++) {
                    float o = xin[mi * 4 + r][ni] + dxv[mi * 4 + r][ni] * (mv + acc[mi][ni][r]);
                    op[(size_t)(m0w + mi * 16 + qd * 4 + r) * 1024 + n0 + ni * 16 + l15] = f2bf(o);
                }
        }
    }
}

// ---------- decay GEMM1: dech = tanh(xw @ dw1), 4-wave K-split ----------
__global__ __launch_bounds__(256) void k_dec1m(const unsigned short* __restrict__ xw16,
                                               const unsigned short* __restrict__ dw1T,
                                               float* __restrict__ dech) {
    __shared__ __align__(16) float red[4][4][64][4];    // 16 KB
    int tid = threadIdx.x;
    int lane = tid & 63, wv = tid >> 6;
    int l15 = lane & 15, qd = lane >> 4;
    int m0 = blockIdx.x * 16;    // grid 256
    fx4 acc[4];
#pragma unroll
    for (int nt = 0; nt < 4; nt++)
#pragma unroll
        for (int r = 0; r < 4; r++) acc[nt][r] = 0.f;
    int kb0 = wv * 256;
#pragma unroll 2
    for (int kb = kb0; kb < kb0 + 256; kb += 32) {
        bh8 af = *(const bh8*)(xw16 + (size_t)(m0 + l15) * 1024 + kb + qd * 8);
#pragma unroll
        for (int nt = 0; nt < 4; nt++) {
            bh8 bf = *(const bh8*)(dw1T + (size_t)(nt * 16 + l15) * 1024 + kb + qd * 8);
            acc[nt] = __builtin_amdgcn_mfma_f32_16x16x32_bf16(af, bf, acc[nt], 0, 0, 0);
        }
    }
#pragma unroll
    for (int nt = 0; nt < 4; nt++)
        *(fx4*)&red[wv][nt][lane][0] = acc[nt];
    __syncthreads();
    if (wv == 0) {
#pragma unroll
        for (int nt = 0; nt < 4; nt++) {
            fx4 s = *(const fx4*)&red[0][nt][lane][0];
            s = s + *(const fx4*)&red[1][nt][lane][0];
            s = s + *(const fx4*)&red[2][nt][lane][0];
            s = s + *(const fx4*)&red[3][nt][lane][0];
#pragma unroll
            for (int r = 0; r < 4; r++)
                dech[(size_t)(m0 + qd * 4 + r) * 64 + nt * 16 + l15] = tanhf(s[r]);
        }
    }
}

// ---------- decay GEMM2: ew = -exp(time_decay + dech @ dw2) ----------
__global__ __launch_bounds__(256) void k_dec2(const float* __restrict__ dech,
                                              const float* __restrict__ dw2,
                                              const float* __restrict__ tdec,
                                              float* __restrict__ ew) {
    __shared__ float hl[8][64];
    int tid = threadIdx.x;
    int tok0 = blockIdx.x * 8;     // grid 512
    {
        int l = tid;        hl[l >> 6][l & 63] = dech[tok0 * 64 + l];
        l = tid + 256;      hl[l >> 6][l & 63] = dech[tok0 * 64 + l];
    }
    __syncthreads();
#pragma unroll 1
    for (int c = 0; c < 4; c++) {
        int d = c * 256 + tid;
        float acc[8] = {};
#pragma unroll 8
        for (int j = 0; j < 64; j++) {
            float wv = dw2[j * 1024 + d];
#pragma unroll
            for (int g = 0; g < 8; g++) acc[g] = fmaf(hl[g][j], wv, acc[g]);
        }
        float td = tdec[d];
#pragma unroll
        for (int g = 0; g < 8; g++) ew[(tok0 + g) * 1024 + d] = -expf(td + acc[g]);
    }
}

// ---------- scan stage 1: per-segment sums (seg = 32) ----------
__global__ __launch_bounds__(64) void k_scan1(const float* __restrict__ ew, float* __restrict__ segsum) {
    int bx = blockIdx.x;            // grid 2048 = 4b x 32seg x 16dch
    int b = bx >> 9, seg = (bx >> 4) & 31, dch = bx & 15;
    int d = dch * 64 + threadIdx.x;
    size_t base = ((size_t)(b * 1024 + seg * 32)) * 1024 + d;
    float s = 0.f;
#pragma unroll 8
    for (int t = 0; t < 32; t++) s += ew[base + (size_t)t * 1024];
    segsum[(b * 32 + seg) * 1024 + d] = s;
}

// ---------- scan stage 2+3 fused: local prefix of segsums + emit packed (cf,cb) ----------
__global__ __launch_bounds__(64) void k_scan3(const float* __restrict__ ew, const float* __restrict__ segsum,
                                              float2* __restrict__ cfb) {
    int bx = blockIdx.x;            // grid 2048
    int b = bx >> 9, seg = (bx >> 4) & 31, dch = bx & 15;
    int d = dch * 64 + threadIdx.x;
    float run = 0.f, pre = 0.f, off16 = 0.f;
#pragma unroll
    for (int s = 0; s < 32; s++) {
        float tv = segsum[(b * 32 + s) * 1024 + d];
        if (s == seg) pre = run;
        if (s == 16) off16 = run;
        run += tv;
    }
    float e512 = ew[((size_t)(b * 1024 + 512)) * 1024 + d];
    float sb = off16;           // cs[511]
    float sf = off16 + e512;    // cs[512]
    float cum = pre;
    size_t base = ((size_t)(b * 1024 + seg * 32)) * 1024 + d;
#pragma unroll 4
    for (int t = 0; t < 32; t++) {
        float prev = cum;
        cum += ew[base + (size_t)t * 1024];
        float2 w;
        w.x = fminf(fmaxf(cum - sf, -60.f), 60.f);
        w.y = fminf(fmaxf(prev - sb, -60.f), 60.f);
        cfb[base + (size_t)t * 1024] = w;
    }
}

// ---------- GEMM engine v5: occupancy-first. BM=128, BN templated, BK=32 ----------
// Wide  (NW=8, BN=256): 512 thr, wave 64x64 (64 AGPR), regs forced <=128 by
//   __launch_bounds__(512,4); LDS ring-3 x 24KB = 72KB -> 2 blocks x 8 waves
//   = 16 waves/CU (4/SIMD). Per wave/tile: 16 MFMA, 8 b128, 3 GLD16 -> vmcnt(3).
// Narrow (NW=4, BN=128): 256 thr, ring-3 x 16KB = 48KB -> 3 blocks/CU (12 waves).
// Zero-conflict swizzle proven in r4: stage gblk = lb ^ ((lr>>1)&3),
// read col qd ^ ((l15>>1)&3). One barrier/tile, counted vmcnt (never 0 till tail).
// modes: 0 fp32 out, 1 silu fp32, 2 q-exp (O1=qf,O2=qb), 3 k-exp, 4 v-transpose (O1=vvt)
// q/k epilogues read the PACKED (cf,cb) float2 array: one dwordx2 per element.
template<int NW, int BNv>
__device__ __forceinline__ void gemm_v5(const unsigned short* __restrict__ A,
                                        const unsigned short* __restrict__ W,
                                        int m0, int n0, int mode,
                                        float* __restrict__ Cf,
                                        unsigned short* __restrict__ O1,
                                        unsigned short* __restrict__ O2,
                                        const float2* __restrict__ cfbp,
                                        char* smem) {
    constexpr int AR = 128 / NW;          // A rows staged per wave
    constexpr int AG = AR / 16;           // GLD16s for A per wave
    constexpr int BR = BNv / NW;          // B rows per wave
    constexpr int BG = BR / 16;
    constexpr int LPW = AG + BG;          // loads per wave per tile
    constexpr int SLOT = (128 + BNv) * 64;   // ring slot bytes
    constexpr int WNC = BNv / 64;

    int tid = threadIdx.x;
    int lane = tid & 63, w = tid >> 6;
    int l15 = lane & 15, qd = lane >> 4;
    int wm = w / WNC, wn = w % WNC;
    int lr = lane >> 2, lb = lane & 3;
    int gblk = lb ^ ((lr >> 1) & 3);      // pre-swizzled global 16B-block
    const unsigned short* aSrc = A + (size_t)(m0 + w * AR + lr) * 1024 + gblk * 8;
    const unsigned short* bSrc = W + (size_t)(n0 + w * BR + lr) * 1024 + gblk * 8;
    int rc = (qd ^ ((l15 >> 1) & 3)) * 8; // swizzled frag col (shorts)
    int arow = (wm * 64 + l15) * 32 + rc;
    int brow = (wn * 64 + l15) * 32 + rc;

    auto stage = [&](int off, int kbv) {
        unsigned short* _sa = (unsigned short*)(smem + off);
        unsigned short* _sb = _sa + 128 * 32;
#pragma unroll
        for (int i = 0; i < AG; ++i)
            GLD16(aSrc + kbv + (size_t)i * 16 * 1024, _sa + (w * AR + i * 16) * 32);
#pragma unroll
        for (int i = 0; i < BG; ++i)
            GLD16(bSrc + kbv + (size_t)i * 16 * 1024, _sb + (w * BR + i * 16) * 32);
    };

    fx4 acc[4][4];
#pragma unroll
    for (int mt = 0; mt < 4; mt++)
#pragma unroll
        for (int nt = 0; nt < 4; nt++)
#pragma unroll
            for (int r = 0; r < 4; r++) acc[mt][nt][r] = 0.f;

    // prologue: tiles 0, 1
    stage(0, 0);
    stage(SLOT, 32);
    if constexpr (LPW == 3) asm volatile("s_waitcnt vmcnt(3)" ::: "memory");
    else                    asm volatile("s_waitcnt vmcnt(4)" ::: "memory");
    BARF();

    int oc = 0, on = SLOT, o2 = 2 * SLOT;
#pragma unroll 1
    for (int t = 0; t < 32; ++t) {
        if (t < 30) stage(o2, (t + 2) * 32);
        const unsigned short* cA = (const unsigned short*)(smem + oc);
        const unsigned short* cB = cA + 128 * 32;
        bh8 a[4], b[4];
#pragma unroll
        for (int mt = 0; mt < 4; ++mt) a[mt] = *(const bh8*)(cA + arow + mt * 512);
#pragma unroll
        for (int nt = 0; nt < 4; ++nt) b[nt] = *(const bh8*)(cB + brow + nt * 512);
        __builtin_amdgcn_s_setprio(1);
#pragma unroll
        for (int nt = 0; nt < 4; ++nt)
#pragma unroll
            for (int mt = 0; mt < 4; ++mt)
                acc[mt][nt] = __builtin_amdgcn_mfma_f32_16x16x32_bf16(a[mt], b[nt], acc[mt][nt], 0, 0, 0);
        __builtin_amdgcn_s_setprio(0);
        asm volatile("s_waitcnt lgkmcnt(0)" ::: "memory");
        if (t < 30) {
            if constexpr (LPW == 3) asm volatile("s_waitcnt vmcnt(3)" ::: "memory");
            else                    asm volatile("s_waitcnt vmcnt(4)" ::: "memory");
        } else if (t == 30) {
            asm volatile("s_waitcnt vmcnt(0)" ::: "memory");
        }
        BARF();
        int tmp = oc; oc = on; on = o2; o2 = tmp;
    }

    // ----- epilogues: per wave 64x64 at (m0 + wm*64, n0 + wn*64) -----
    int mb = m0 + wm * 64, nb = n0 + wn * 64;
    if (mode <= 1) {
#pragma unroll
        for (int mt = 0; mt < 4; mt++)
#pragma unroll
            for (int nt = 0; nt < 4; nt++)
#pragma unroll
                for (int r = 0; r < 4; r++) {
                    float v = acc[mt][nt][r];
                    if (mode == 1) v = v / (1.f + __expf(-v));
                    Cf[(size_t)(mb + mt * 16 + qd * 4 + r) * 1024 + nb + nt * 16 + l15] = v;
                }
    } else if (mode <= 3) {
        float s1 = (mode == 2) ? 1.f : -1.f;
#pragma unroll
        for (int mt = 0; mt < 4; mt++)
#pragma unroll
            for (int nt = 0; nt < 4; nt++)
#pragma unroll
                for (int r = 0; r < 4; r++) {
                    size_t idx = (size_t)(mb + mt * 16 + qd * 4 + r) * 1024 + nb + nt * 16 + l15;
                    float v = acc[mt][nt][r];
                    float2 c2 = cfbp[idx];
                    O1[idx] = f2bf(v * __expf(s1 * c2.x));
                    O2[idx] = f2bf(v * __expf(-s1 * c2.y));
                }
    } else {
        // V transpose: vvt[(b*1024 + d)][t]; T[BNv d][136] shorts
        unsigned short* T = (unsigned short*)smem;
        int bq = m0 >> 10, t0 = m0 & 1023;
#pragma unroll
        for (int mt = 0; mt < 4; mt++)
#pragma unroll
            for (int nt = 0; nt < 4; nt++) {
                int dl = wn * 64 + nt * 16 + l15;
                int tl = wm * 64 + mt * 16 + qd * 4;
                uint2 pk2;
                pk2.x = pkbf(acc[mt][nt][0], acc[mt][nt][1]);
                pk2.y = pkbf(acc[mt][nt][2], acc[mt][nt][3]);
                *(uint2*)(T + dl * 136 + tl) = pk2;
            }
        asm volatile("s_waitcnt lgkmcnt(0)" ::: "memory");
        BARF();
#pragma unroll
        for (int p = 0; p < 8; ++p) {
            int idx = p * (NW * 64) + tid;
            int dd = idx >> 4, u = idx & 15;
            uint4 vv = *(const uint4*)(T + dd * 136 + u * 8);
            *(uint4*)(O1 + (size_t)(bq * 1024 + n0 + dd) * 1024 + t0 + u * 8) = vv;
        }
    }
}

__global__ __launch_bounds__(512, 4) void k_qkvg(const unsigned short* __restrict__ xr16,
                                                 const unsigned short* __restrict__ xk16,
                                                 const unsigned short* __restrict__ xv16,
                                                 const unsigned short* __restrict__ xg16,
                                                 const unsigned short* __restrict__ Wrb,
                                                 const unsigned short* __restrict__ Wkb,
                                                 const unsigned short* __restrict__ Wvb,
                                                 const unsigned short* __restrict__ Wgb,
                                                 unsigned short* __restrict__ qf, unsigned short* __restrict__ qb,
                                                 unsigned short* __restrict__ kf, unsigned short* __restrict__ kb,
                                                 unsigned short* __restrict__ vvt,
                                                 float* __restrict__ gg,
                                                 const float2* __restrict__ cfb) {
    __shared__ __align__(16) char smem[73728];
    // bijective XCD swizzle (512 % 8 == 0): XCD x gets 64 contiguous work ids
    int flat = blockIdx.x;
    int wkid = (flat & 7) * 64 + (flat >> 3);
    int gy = wkid >> 7;                        // which GEMM (128 tiles each)
    int rem = wkid & 127;
    int m0 = (rem >> 2) * 128, n0 = (rem & 3) * 256;
    const unsigned short* Ap = (gy == 0) ? xr16 : (gy == 1) ? xk16 : (gy == 2) ? xv16 : xg16;
    const unsigned short* Wp = (gy == 0) ? Wrb : (gy == 1) ? Wkb : (gy == 2) ? Wvb : Wgb;
    int mode = (gy == 0) ? 2 : (gy == 1) ? 3 : (gy == 2) ? 4 : 1;
    unsigned short* o1 = (gy == 0) ? qf : (gy == 1) ? kf : (gy == 2) ? vvt : nullptr;
    unsigned short* o2 = (gy == 0) ? qb : (gy == 1) ? kb : nullptr;
    float* cfo = (gy == 3) ? gg : nullptr;
    gemm_v5<8, 256>(Ap, Wp, m0, n0, mode, cfo, o1, o2, cfb, smem);
}

__global__ __launch_bounds__(256, 3) void k_gemmo(const unsigned short* __restrict__ z16,
                                                  const unsigned short* __restrict__ Wob,
                                                  float* __restrict__ out) {
    __shared__ __align__(16) char smem[49152];
    int flat = blockIdx.x;                     // grid 256 (256 % 8 == 0)
    int wkid = (flat & 7) * 32 + (flat >> 3);
    int m0 = (wkid >> 3) * 128, n0 = (wkid & 7) * 128;
    gemm_v5<4, 128>(z16, Wob, m0, n0, 0, out, nullptr, nullptr, nullptr, smem);
}

// ---------- attention v5: ring-2 staged + fused GroupNorm*g epilogue -> z16 ----------
// setprio now wraps the whole per-tile compute once (was 16 toggles per j-tile).
__global__ __launch_bounds__(256, 2) void k_attn(const unsigned short* __restrict__ qf,
                                                 const unsigned short* __restrict__ qb,
                                                 const unsigned short* __restrict__ kf,
                                                 const unsigned short* __restrict__ kb,
                                                 const unsigned short* __restrict__ vvt,
                                                 const float* __restrict__ gg,
                                                 const float* __restrict__ lnw,
                                                 const float* __restrict__ lnb,
                                                 unsigned short* __restrict__ z16) {
    __shared__ __align__(16) char smem[65536];
    unsigned short* S = (unsigned short*)smem;
    int tid = threadIdx.x;
    int w = tid >> 6, lane = tid & 63, l15 = lane & 15, qd = lane >> 4;
    int bid = blockIdx.x;            // grid 512 = 64 bh x 8 itile, XCD-swizzled
    int bh = (bid & 7) + ((bid >> 6) << 3);
    int ib = (bid >> 3) & 7;
    int b = bh >> 4, h = bh & 15;
    int i0w = ib * 128 + w * 32;
    int bt0 = b * 1024;
    const unsigned short* vrow = vvt + (size_t)(b * 1024 + h * 64 + w * 16 + l15) * 1024 + qd * 8;
    int fmax = (i0w + 31) >> 6;
    int bmin = i0w >> 6;
    int srcA = l15 + ((lane & 16) << 1);
    int srcB = srcA + 16;
    fx4 yacc[4][2];
#pragma unroll
    for (int mt = 0; mt < 4; mt++)
#pragma unroll
        for (int nt = 0; nt < 2; nt++)
#pragma unroll
            for (int r = 0; r < 4; r++) yacc[mt][nt][r] = 0.f;

    for (int phase = 0; phase < 2; phase++) {
        const unsigned short* Q = phase ? qb : qf;
        const unsigned short* K = phase ? kb : kf;
        bh8 qfr[2][2];
#pragma unroll
        for (int nt = 0; nt < 2; nt++)
#pragma unroll
            for (int ks = 0; ks < 2; ks++)
                qfr[nt][ks] = *(const bh8*)(Q + (size_t)(bt0 + i0w + nt * 16 + l15) * 1024
                                              + h * 64 + ks * 32 + qd * 8);
        int jlo = phase == 0 ? 0 : 2 * ib;            // both ranges have EVEN length
        int nr  = phase == 0 ? (ib + 1) : (8 - ib);   // rounds of 2 j-tiles
        const unsigned short* krow = K + (size_t)(bt0 + w * 16 + l15) * 1024 + h * 64 + qd * 8;

#define ASTAGE(jt2v, rb) do { \
    _Pragma("unroll") \
    for (int u = 0; u < 2; ++u) { \
        size_t jbs = (size_t)((jt2v) + u) * 64; \
        unsigned short* kd = S + (rb) * 16384 + u * 4096 + w * 512; \
        unsigned short* vd = S + (rb) * 16384 + 8192 + u * 4096 + w * 512; \
        GLD16(krow + jbs * 1024,      kd); \
        GLD16(krow + jbs * 1024 + 32, kd + 2048); \
        GLD16(vrow + jbs,             vd); \
        GLD16(vrow + jbs + 32,        vd + 2048); \
    } \
} while (0)

        ASTAGE(jlo, 0);
        for (int ridx = 0; ridx < nr; ++ridx) {
            int jt2 = jlo + ridx * 2;
            if (ridx + 1 < nr) {
                ASTAGE(jt2 + 2, (ridx + 1) & 1);
                asm volatile("s_waitcnt vmcnt(8)" ::: "memory");   // this round resident
            } else {
                asm volatile("s_waitcnt vmcnt(0)" ::: "memory");
            }
            BARF();
            int rb = ridx & 1;
#pragma unroll
            for (int u = 0; u < 2; ++u) {
                int jt = jt2 + u;
                int jb = jt * 64;
                const unsigned short* bK = S + rb * 16384 + u * 4096;
                const unsigned short* bV = bK + 8192;
                bool active = (phase == 0) ? (jt <= fmax) : (jt >= bmin);
                if (!active) continue;
                bool needmask = (phase == 0) ? (jb + 63 > i0w) : (i0w + 31 >= jb);
                bh8 kc[8];
#pragma unroll
                for (int fi = 0; fi < 8; fi++)
                    kc[fi] = *(const bh8*)(bK + fi * 512 + lane * 8);
                fx4 sacc[4][2];
#pragma unroll
                for (int mt = 0; mt < 4; mt++)
#pragma unroll
                    for (int nt = 0; nt < 2; nt++)
#pragma unroll
                        for (int r = 0; r < 4; r++) sacc[mt][nt][r] = 0.f;
                __builtin_amdgcn_s_setprio(1);
#pragma unroll
                for (int ks = 0; ks < 2; ks++)
#pragma unroll
                    for (int mt = 0; mt < 4; mt++)
#pragma unroll
                        for (int nt = 0; nt < 2; nt++)
                            sacc[mt][nt] = __builtin_amdgcn_mfma_f32_16x16x32_bf16(kc[ks * 4 + mt], qfr[nt][ks], sacc[mt][nt], 0, 0, 0);
                uint2 pk[4][2];
#pragma unroll
                for (int mt = 0; mt < 4; mt++)
#pragma unroll
                    for (int nt = 0; nt < 2; nt++) {
                        fx4 s = sacc[mt][nt];
                        if (needmask) {
                            int ii = i0w + nt * 16 + l15;
                            int jj0 = jb + mt * 16 + qd * 4;
#pragma unroll
                            for (int r = 0; r < 4; r++) {
                                bool keep = (phase == 0) ? (ii >= jj0 + r) : (ii < jj0 + r);
                                if (!keep) s[r] = 0.f;
                            }
                        }
                        pk[mt][nt].x = pkbf(s[0], s[1]);
                        pk[mt][nt].y = pkbf(s[2], s[3]);
                    }
                bh8 vc[8];
#pragma unroll
                for (int fi = 0; fi < 8; fi++)
                    vc[fi] = *(const bh8*)(bV + fi * 512 + lane * 8);
#pragma unroll
                for (int ks2 = 0; ks2 < 2; ks2++) {
#pragma unroll
                    for (int nt = 0; nt < 2; nt++) {
                        int lox  = __shfl((int)pk[2 * ks2][nt].x,     srcA);
                        int hix  = __shfl((int)pk[2 * ks2 + 1][nt].x, srcA);
                        int loy  = __shfl((int)pk[2 * ks2][nt].y,     srcA);
                        int hiy  = __shfl((int)pk[2 * ks2 + 1][nt].y, srcA);
                        int lox2 = __shfl((int)pk[2 * ks2][nt].x,     srcB);
                        int hix2 = __shfl((int)pk[2 * ks2 + 1][nt].x, srcB);
                        int loy2 = __shfl((int)pk[2 * ks2][nt].y,     srcB);
                        int hiy2 = __shfl((int)pk[2 * ks2 + 1][nt].y, srcB);
                        union { int4 i; bh8 h; } cv;
                        cv.i.x = (qd & 2) ? hix  : lox;
                        cv.i.y = (qd & 2) ? hiy  : loy;
                        cv.i.z = (qd & 2) ? hix2 : lox2;
                        cv.i.w = (qd & 2) ? hiy2 : loy2;
#pragma unroll
                        for (int mt = 0; mt < 4; mt++)
                            yacc[mt][nt] = __builtin_amdgcn_mfma_f32_16x16x32_bf16(vc[ks2 * 4 + mt], cv.h, yacc[mt][nt], 0, 0, 0);
                    }
                }
                __builtin_amdgcn_s_setprio(0);
            }
            BARF();   // all waves done reading this buffer before it is restaged
        }
#undef ASTAGE
    }
    // ----- fused GroupNorm * g epilogue -> z16 -----
#pragma unroll
    for (int nt = 0; nt < 2; nt++) {
        float s = 0.f, s2 = 0.f;
#pragma unroll
        for (int mt = 0; mt < 4; mt++)
#pragma unroll
            for (int r = 0; r < 4; r++) {
                float v = yacc[mt][nt][r];
                s += v;
                s2 += v * v;
            }
        s  += __shfl_xor(s, 16, 64);
        s2 += __shfl_xor(s2, 16, 64);
        s  += __shfl_xor(s, 32, 64);
        s2 += __shfl_xor(s2, 32, 64);
        float mu = s * (1.f / 64.f);
        float var = s2 * (1.f / 64.f) - mu * mu;
        float inv = rsqrtf(var + 6.4e-4f);
        size_t tokbase = (size_t)(bt0 + i0w + nt * 16 + l15) * 1024 + h * 64;
#pragma unroll
        for (int mt = 0; mt < 4; mt++) {
            int dl = mt * 16 + qd * 4;
            float4 lw = *(const float4*)(lnw + h * 64 + dl);
            float4 lb = *(const float4*)(lnb + h * 64 + dl);
            float4 gv = *(const float4*)(gg + tokbase + dl);
            float z0 = ((yacc[mt][nt][0] - mu) * inv * lw.x + lb.x) * gv.x;
            float z1 = ((yacc[mt][nt][1] - mu) * inv * lw.y + lb.y) * gv.y;
            float z2 = ((yacc[mt][nt][2] - mu) * inv * lw.z + lb.z) * gv.z;
            float z3 = ((yacc[mt][nt][3] - mu) * inv * lw.w + lb.w) * gv.w;
            uint2 o;
            o.x = pkbf(z0, z1);
            o.y = pkbf(z2, z3);
            *(uint2*)(z16 + tokbase + dl) = o;
        }
    }
}

extern "C" void kernel_launch(void* const* d_in, const int* in_sizes, int n_in,
                              void* d_out, int out_size, void* d_ws, size_t ws_size,
                              hipStream_t stream) {
    const float* x     = (const float*)d_in[0];
    const float* maa_x = (const float*)d_in[1];
    const float* maa_w = (const float*)d_in[2];
    const float* maa_k = (const float*)d_in[3];
    const float* maa_v = (const float*)d_in[4];
    const float* maa_r = (const float*)d_in[5];
    const float* maa_g = (const float*)d_in[6];
    const float* w1    = (const float*)d_in[7];
    const float* w2    = (const float*)d_in[8];
    const float* tdec  = (const float*)d_in[9];
    const float* dw1   = (const float*)d_in[10];
    const float* dw2   = (const float*)d_in[11];
    const float* W_r   = (const float*)d_in[12];
    const float* W_k   = (const float*)d_in[13];
    const float* W_v   = (const float*)d_in[14];
    const float* W_g   = (const float*)d_in[15];
    const float* W_o   = (const float*)d_in[16];
    const float* lnw   = (const float*)d_in[17];
    const float* lnb   = (const float*)d_in[18];

    float* ws = (float*)d_ws;
    size_t o = 0;
    float* dech   = ws + o; o += 262144;
    float* segsum = ws + o; o += 131072;
    float* ew     = ws + o; o += 4194304;
    float2* cfb   = (float2*)(ws + o); o += 8388608;   // packed (cf,cb), 33.6 MB
    float* gg     = ws + o; o += 4194304;
    unsigned short* us = (unsigned short*)(ws + o);
    size_t u = 0;
    unsigned short* xmix16 = us + u; u += 4194304;
    unsigned short* xw16 = us + u; u += 4194304;
    unsigned short* xr16 = us + u; u += 4194304;   // also z16 after gemm4
    unsigned short* xk16 = us + u; u += 4194304;
    unsigned short* xv16 = us + u; u += 4194304;
    unsigned short* xg16 = us + u; u += 4194304;
    unsigned short* qf   = us + u; u += 4194304;
    unsigned short* qb   = us + u; u += 4194304;
    unsigned short* kf   = us + u; u += 4194304;
    unsigned short* kb   = us + u; u += 4194304;
    unsigned short* vvt  = us + u; u += 4194304;
    unsigned short* Wrb  = us + u; u += 1048576;
    unsigned short* Wkb  = us + u; u += 1048576;
    unsigned short* Wvb  = us + u; u += 1048576;
    unsigned short* Wgb  = us + u; u += 1048576;
    unsigned short* Wob  = us + u; u += 1048576;
    unsigned short* w1T  = us + u; u += 163840;
    unsigned short* dw1T = us + u; u += 65536;
    unsigned short* xxx16 = us + u; u += 655360;
    unsigned short* w2T16 = us + u; u += 163840;
    unsigned short* z16 = xr16;    // dead after gemm4; attn writes gn output here

    k_prep<<<dim3(640, 7), 256, 0, stream>>>(W_r, W_k, W_v, W_g, W_o, w1, dw1, w2,
                                             Wrb, Wkb, Wvb, Wgb, Wob, w1T, dw1T, w2T16);
    k_mixx<<<4096, 256, 0, stream>>>(x, maa_x, xmix16);
    k_xxx2<<<256, 256, 0, stream>>>(xmix16, w1T, xxx16);
    k_mmix<<<dim3(16, 32), 256, 0, stream>>>(x, xxx16, w2T16, maa_w, maa_k, maa_v, maa_r, maa_g,
                                             xw16, xk16, xv16, xr16, xg16);
    k_dec1m<<<256, 256, 0, stream>>>(xw16, dw1T, dech);
    k_dec2<<<512, 256, 0, stream>>>(dech, dw2, tdec, ew);
    k_scan1<<<2048, 64, 0, stream>>>(ew, segsum);
    k_scan3<<<2048, 64, 0, stream>>>(ew, segsum, cfb);
    k_qkvg<<<dim3(512), dim3(512), 0, stream>>>(xr16, xk16, xv16, xg16, Wrb, Wkb, Wvb, Wgb,
                                                qf, qb, kf, kb, vvt, gg, cfb);
    k_attn<<<512, 256, 0, stream>>>(qf, qb, kf, kb, vvt, gg, lnw, lnb, z16);
    k_gemmo<<<256, 256, 0, stream>>>(z16, Wob, (float*)d_out);
}